// Round 8
// baseline (235.144 us; speedup 1.0000x reference)
//
#include <hip/hip_runtime.h>
#include <hip/hip_bf16.h>
#include <math.h>

#define NB 8192
#define DD 512
#define HH 256
#define BM 128
#define BN 256
#define BK 32
#define KT (DD / BK)       // 16 k-tiles in sim
#define NSLOT 32           // col-group slots per row
#define NSUB 2             // sub-slots (direct h=0 / transposed parity)
#define ROWKEYS (NSLOT * NSUB * 3)   // 192 keys per row
#define NCAND 8

typedef unsigned short ushortT;
typedef __attribute__((ext_vector_type(8))) short bf16x8;
typedef __attribute__((ext_vector_type(4))) float f32x4;

#define AS1(p) ((const __attribute__((address_space(1))) void*)(p))
#define AS3(p) ((__attribute__((address_space(3))) void*)(p))

__device__ __forceinline__ ushortT bf16rne(float f) {
    unsigned u = __float_as_uint(f);
    unsigned r = u + 0x7FFFu + ((u >> 16) & 1u);
    return (ushortT)(r >> 16);
}
__device__ __forceinline__ float bf16tof(ushortT h) {
    return __uint_as_float(((unsigned)h) << 16);
}

// ---------------- Kernel 0: prep — split sess to bf16 hi/lo; transpose+split W1,W2 ----------------
__global__ __launch_bounds__(256)
void prep_kernel(const float* __restrict__ sess, const float* __restrict__ W1,
                 const float* __restrict__ W2,
                 ushortT* __restrict__ sess_hi, ushortT* __restrict__ sess_lo,
                 ushortT* __restrict__ w1t_hi, ushortT* __restrict__ w1t_lo,
                 ushortT* __restrict__ w2t_hi, ushortT* __restrict__ w2t_lo) {
    const int b = blockIdx.x, t = threadIdx.x;
    if (b < 2048) {
        size_t i = (size_t)b * 2048 + t * 8;
        float4 f0 = *(const float4*)&sess[i];
        float4 f1 = *(const float4*)&sess[i + 4];
        float f[8] = {f0.x, f0.y, f0.z, f0.w, f1.x, f1.y, f1.z, f1.w};
        unsigned hp[4], lp[4];
#pragma unroll
        for (int j = 0; j < 4; ++j) {
            ushortT h0 = bf16rne(f[2 * j]), h1 = bf16rne(f[2 * j + 1]);
            ushortT l0 = bf16rne(f[2 * j] - bf16tof(h0));
            ushortT l1 = bf16rne(f[2 * j + 1] - bf16tof(h1));
            hp[j] = (unsigned)h0 | ((unsigned)h1 << 16);
            lp[j] = (unsigned)l0 | ((unsigned)l1 << 16);
        }
        *(uint4*)&sess_hi[i] = *(uint4*)hp;
        *(uint4*)&sess_lo[i] = *(uint4*)lp;
    } else if (b < 2112) {
        int o = (b - 2048) * 2048 + t * 8;
        int k = o >> 8, c = o & 255;
        float4 f0 = *(const float4*)&W1[(size_t)k * 256 + c];
        float4 f1 = *(const float4*)&W1[(size_t)k * 256 + c + 4];
        float f[8] = {f0.x, f0.y, f0.z, f0.w, f1.x, f1.y, f1.z, f1.w};
#pragma unroll
        for (int j = 0; j < 8; ++j) {
            ushortT h = bf16rne(f[j]);
            w1t_hi[(size_t)(c + j) * 512 + k] = h;
            w1t_lo[(size_t)(c + j) * 512 + k] = bf16rne(f[j] - bf16tof(h));
        }
    } else {
        int o = (b - 2112) * 2048 + t * 8;
        int k = o >> 9, c = o & 511;
        float4 f0 = *(const float4*)&W2[(size_t)k * 512 + c];
        float4 f1 = *(const float4*)&W2[(size_t)k * 512 + c + 4];
        float f[8] = {f0.x, f0.y, f0.z, f0.w, f1.x, f1.y, f1.z, f1.w};
#pragma unroll
        for (int j = 0; j < 8; ++j) {
            ushortT h = bf16rne(f[j]);
            w2t_hi[(size_t)(c + j) * 256 + k] = h;
            w2t_lo[(size_t)(c + j) * 256 + k] = bf16rne(f[j] - bf16tof(h));
        }
    }
}

// -------- Kernel 1/2: split-bf16 MFMA GEMM, C = A @ B^T (+bias), 64x256 tile --------
template <int KDIM, int NOUT, int EPI>
__global__ __launch_bounds__(256)
void mlp_gemm(const ushortT* __restrict__ Ahi, const ushortT* __restrict__ Alo,
              const ushortT* __restrict__ Bhi, const ushortT* __restrict__ Blo,
              const float* __restrict__ bias,
              ushortT* __restrict__ Ohi, ushortT* __restrict__ Olo,
              float* __restrict__ Of, ushortT* __restrict__ Ob) {
    __shared__ short gsmem[2 * 20480];
    const int KTILES = KDIM / BK;
    const int t = threadIdx.x;
    const int w = t >> 6, l = t & 63;
    const int wr = w >> 1, wc = w & 1;
    const int tx = l & 15, tg = l >> 4;
    const int rb = blockIdx.x * 64;
    const int cb = blockIdx.y * 256;

    const int rin = l >> 2;
    const int tgs = (l & 3) ^ ((rin >> 1) & 3);
    const int loff = tx * BK + ((tg ^ ((tx >> 1) & 3)) << 3);

    f32x4 acc[2][8];
#pragma unroll
    for (int i = 0; i < 2; ++i)
#pragma unroll
        for (int j = 0; j < 8; ++j) acc[i][j] = (f32x4){0.f, 0.f, 0.f, 0.f};

#define GSTAGE(buf, k0v)                                                                     \
    {                                                                                        \
        _Pragma("unroll")                                                                    \
        for (int q = 0; q < 10; ++q) {                                                       \
            int c = w * 10 + q;                                                              \
            const ushortT* src; int row; int lofs;                                           \
            if (c < 4)       { src = Ahi; row = rb + c * 16 + rin;        lofs = 0     + c * 512; }        \
            else if (c < 8)  { src = Alo; row = rb + (c - 4) * 16 + rin;  lofs = 2048  + (c - 4) * 512; }  \
            else if (c < 24) { src = Bhi; row = cb + (c - 8) * 16 + rin;  lofs = 4096  + (c - 8) * 512; }  \
            else             { src = Blo; row = cb + (c - 24) * 16 + rin; lofs = 12288 + (c - 24) * 512; } \
            const ushortT* g = src + (size_t)row * KDIM + (k0v) + tgs * 8;                   \
            __builtin_amdgcn_global_load_lds(AS1(g), AS3(gsmem + (buf) * 20480 + lofs + l * 8), 16, 0, 0); \
        }                                                                                    \
    }

#define GCOMPUTE(kt)                                                                         \
    {                                                                                        \
        const short* Bu = gsmem + ((kt) & 1) * 20480;                                        \
        bf16x8 ah[2], al[2], bh[8], bl[8];                                                   \
        _Pragma("unroll")                                                                    \
        for (int mi = 0; mi < 2; ++mi) {                                                     \
            ah[mi] = *(const bf16x8*)&Bu[0 + (wr * 2 + mi) * 512 + loff];                    \
            al[mi] = *(const bf16x8*)&Bu[2048 + (wr * 2 + mi) * 512 + loff];                 \
        }                                                                                    \
        _Pragma("unroll")                                                                    \
        for (int nj = 0; nj < 8; ++nj) {                                                     \
            bh[nj] = *(const bf16x8*)&Bu[4096 + (wc * 8 + nj) * 512 + loff];                 \
            bl[nj] = *(const bf16x8*)&Bu[12288 + (wc * 8 + nj) * 512 + loff];                \
        }                                                                                    \
        asm volatile("s_waitcnt lgkmcnt(0)" ::: "memory");                                   \
        __builtin_amdgcn_sched_barrier(0);                                                   \
        __builtin_amdgcn_s_barrier();                                                        \
        __builtin_amdgcn_sched_barrier(0);                                                   \
        _Pragma("unroll")                                                                    \
        for (int mi = 0; mi < 2; ++mi)                                                       \
            _Pragma("unroll")                                                                \
            for (int nj = 0; nj < 8; ++nj) {                                                 \
                acc[mi][nj] = __builtin_amdgcn_mfma_f32_16x16x32_bf16(ah[mi], bh[nj], acc[mi][nj], 0, 0, 0); \
                acc[mi][nj] = __builtin_amdgcn_mfma_f32_16x16x32_bf16(ah[mi], bl[nj], acc[mi][nj], 0, 0, 0); \
                acc[mi][nj] = __builtin_amdgcn_mfma_f32_16x16x32_bf16(al[mi], bh[nj], acc[mi][nj], 0, 0, 0); \
            }                                                                                \
    }

    GSTAGE(0, 0);
    for (int kt = 0; kt < KTILES - 1; ++kt) {
        GSTAGE((kt + 1) & 1, (kt + 1) * BK);
        asm volatile("s_waitcnt vmcnt(10)" ::: "memory");
        __builtin_amdgcn_sched_barrier(0);
        __builtin_amdgcn_s_barrier();
        __builtin_amdgcn_sched_barrier(0);
        GCOMPUTE(kt);
    }
    asm volatile("s_waitcnt vmcnt(0)" ::: "memory");
    __builtin_amdgcn_sched_barrier(0);
    __builtin_amdgcn_s_barrier();
    __builtin_amdgcn_sched_barrier(0);
    GCOMPUTE(KTILES - 1);
#undef GSTAGE
#undef GCOMPUTE

#pragma unroll
    for (int mi = 0; mi < 2; ++mi) {
#pragma unroll
        for (int nj = 0; nj < 8; ++nj) {
            int col = cb + wc * 128 + nj * 16 + tx;
            float bv = bias[col];
#pragma unroll
            for (int rr = 0; rr < 4; ++rr) {
                int row = rb + wr * 32 + mi * 16 + tg * 4 + rr;
                float v = acc[mi][nj][rr] + bv;
                if (EPI == 0) {
                    v = fmaxf(v, 0.f);
                    ushortT h = bf16rne(v);
                    Ohi[(size_t)row * NOUT + col] = h;
                    Olo[(size_t)row * NOUT + col] = bf16rne(v - bf16tof(h));
                } else {
                    Of[(size_t)row * NOUT + col] = v;
                    Ob[(size_t)row * NOUT + col] = bf16rne(v);
                }
            }
        }
    }
}

// ---- packed-key top-3 helpers (u32 key = monotone(f32)&~0x1FFF | (8191-idx)) ----
__device__ __forceinline__ void ins3k(unsigned key, unsigned& k0, unsigned& k1, unsigned& k2) {
    bool g0 = key > k0, g1 = key > k1, g2 = key > k2;
    k2 = g1 ? k1 : (g2 ? key : k2);
    k1 = g0 ? k0 : (g1 ? key : k1);
    k0 = g0 ? key : k0;
}
__device__ __forceinline__ void merge3k(unsigned& a0, unsigned& a1, unsigned& a2,
                                        unsigned b0, unsigned b1, unsigned b2) {
    unsigned m0 = a0 > b0 ? a0 : b0;
    bool c0 = a0 > b0;
    unsigned ca1 = c0 ? a1 : b1;
    unsigned cb0 = c0 ? b0 : a0;
    unsigned ca2 = c0 ? a2 : b2;
    unsigned cb1 = c0 ? b1 : a1;
    bool c1 = ca1 > cb0;
    unsigned m1 = c1 ? ca1 : cb0;
    unsigned x = c1 ? ca2 : ca1;
    unsigned y = c1 ? cb0 : cb1;
    unsigned m2 = x > y ? x : y;
    a0 = m0; a1 = m1; a2 = m2;
}
__device__ __forceinline__ unsigned packkey(float f, unsigned idx) {
    unsigned u = __float_as_uint(f);
    unsigned tt = (unsigned)((int)u >> 31) | 0x80000000u;
    return ((u ^ tt) & 0xFFFFE000u) | (8191u - idx);
}

// ------------- Kernel 3: symmetric bf16 MFMA sim (128x256 blocks, upper triangle) -------------
// block (ib, J) active iff ib <= 2J+1. Direct epilogue -> pkeys[row][J][0]; strictly-upper
// blocks also emit transposed per-col top-3 -> pkeys[col][ib>>1][ib&1].
__global__ __launch_bounds__(256)
void sim_mfma_kernel(const short* __restrict__ projb, unsigned* __restrict__ pkeys) {
    const int ib = blockIdx.x, Jb = blockIdx.y;
    if (ib > 2 * Jb + 1) return;
    const bool do_tr = (ib < 2 * Jb);   // strictly-upper: emit transposed contribution

    __shared__ short smem[2 * BM * BK + 2 * BN * BK];   // 48 KB
    short* As = smem;
    short* Bs = smem + 2 * BM * BK;
    unsigned* evu = (unsigned*)smem;          // direct overlay [128][25]
    unsigned* evt = (unsigned*)smem + 3200;   // transposed overlay [256][6]

    const int t = threadIdx.x;
    const int w = t >> 6, l = t & 63;
    const int wr = w >> 1, wc = w & 1;
    const int tx = l & 15, tg = l >> 4;
    const int rb = ib * BM;
    const int jb = Jb * BN;

    const int rin = l >> 2;
    const int tgs = (l & 3) ^ ((rin >> 1) & 3);
    const int loff = tx * BK + ((tg ^ ((tx >> 1) & 3)) << 3);

    f32x4 acc[4][8];
#pragma unroll
    for (int i = 0; i < 4; ++i)
#pragma unroll
        for (int j = 0; j < 8; ++j) acc[i][j] = (f32x4){0.f, 0.f, 0.f, 0.f};

#define STAGE(buf, k0)                                                                      \
    {                                                                                       \
        _Pragma("unroll")                                                                   \
        for (int q = 0; q < 6; ++q) {                                                       \
            int c = w * 6 + q;                                                              \
            if (c < 8) {                                                                    \
                const short* g = projb + (size_t)(rb + c * 16 + rin) * DD + (k0) + tgs * 8; \
                __builtin_amdgcn_global_load_lds(AS1(g), AS3(As + (buf) * (BM * BK) + c * 512), 16, 0, 0); \
            } else {                                                                        \
                int cb = c - 8;                                                             \
                const short* g = projb + (size_t)(jb + cb * 16 + rin) * DD + (k0) + tgs * 8; \
                __builtin_amdgcn_global_load_lds(AS1(g), AS3(Bs + (buf) * (BN * BK) + cb * 512), 16, 0, 0); \
            }                                                                               \
        }                                                                                   \
    }

#define COMPUTE(kt)                                                                          \
    {                                                                                        \
        const short* Ab = As + ((kt) & 1) * (BM * BK);                                       \
        const short* Bb = Bs + ((kt) & 1) * (BN * BK);                                       \
        bf16x8 af[4], bfr[8];                                                                \
        _Pragma("unroll")                                                                    \
        for (int mi = 0; mi < 4; ++mi)                                                       \
            af[mi] = *(const bf16x8*)&Ab[(wr * 64 + mi * 16) * BK + loff];                   \
        _Pragma("unroll")                                                                    \
        for (int nj = 0; nj < 8; ++nj)                                                       \
            bfr[nj] = *(const bf16x8*)&Bb[(wc * 128 + nj * 16) * BK + loff];                 \
        asm volatile("s_waitcnt lgkmcnt(0)" ::: "memory");                                   \
        __builtin_amdgcn_sched_barrier(0);                                                   \
        __builtin_amdgcn_s_barrier();                                                        \
        __builtin_amdgcn_sched_barrier(0);                                                   \
        _Pragma("unroll")                                                                    \
        for (int mi = 0; mi < 4; ++mi)                                                       \
            _Pragma("unroll")                                                                \
            for (int nj = 0; nj < 8; ++nj)                                                   \
                acc[mi][nj] = __builtin_amdgcn_mfma_f32_16x16x32_bf16(af[mi], bfr[nj], acc[mi][nj], 0, 0, 0); \
    }

    STAGE(0, 0);
    for (int kt = 0; kt < KT - 1; ++kt) {
        STAGE((kt + 1) & 1, (kt + 1) * BK);
        asm volatile("s_waitcnt vmcnt(6)" ::: "memory");
        __builtin_amdgcn_sched_barrier(0);
        __builtin_amdgcn_s_barrier();
        __builtin_amdgcn_sched_barrier(0);
        COMPUTE(kt);
    }
    asm volatile("s_waitcnt vmcnt(0)" ::: "memory");
    __builtin_amdgcn_sched_barrier(0);
    __builtin_amdgcn_s_barrier();
    __builtin_amdgcn_sched_barrier(0);
    COMPUTE(KT - 1);
#undef STAGE
#undef COMPUTE

    __syncthreads();   // K-loop done everywhere before LDS overlay

    // ---- direct epilogue: per-row top3 over cols ----
    unsigned cinv[8];
#pragma unroll
    for (int nj = 0; nj < 8; ++nj)
        cinv[nj] = 8191u - (unsigned)(jb + wc * 128 + nj * 16 + tx);
#pragma unroll
    for (int mi = 0; mi < 4; ++mi) {
#pragma unroll
        for (int rr = 0; rr < 4; ++rr) {
            unsigned k0 = 0, k1 = 0, k2 = 0;
#pragma unroll
            for (int nj = 0; nj < 8; ++nj) {
                unsigned u = __float_as_uint(acc[mi][nj][rr]);
                unsigned tt = (unsigned)((int)u >> 31) | 0x80000000u;
                unsigned key = ((u ^ tt) & 0xFFFFE000u) | cinv[nj];
                ins3k(key, k0, k1, k2);
            }
#pragma unroll
            for (int s = 1; s <= 2; s <<= 1) {
                unsigned b0 = (unsigned)__shfl_xor((int)k0, s, 64);
                unsigned b1 = (unsigned)__shfl_xor((int)k1, s, 64);
                unsigned b2 = (unsigned)__shfl_xor((int)k2, s, 64);
                merge3k(k0, k1, k2, b0, b1, b2);
            }
            if ((tx & 3) == 0) {
                int lrow = wr * 64 + mi * 16 + tg * 4 + rr;
                unsigned* e = &evu[lrow * 25 + (wc * 4 + (tx >> 2)) * 3];
                e[0] = k0; e[1] = k1; e[2] = k2;
            }
        }
    }

    // ---- transposed epilogue (strictly-upper blocks): per-col top3 over rows ----
    if (do_tr) {
#pragma unroll
        for (int nj = 0; nj < 8; ++nj) {
            unsigned k0 = 0, k1 = 0, k2 = 0;
#pragma unroll
            for (int mi = 0; mi < 4; ++mi) {
#pragma unroll
                for (int rr = 0; rr < 4; ++rr) {
                    unsigned idx = (unsigned)(rb + wr * 64 + mi * 16 + tg * 4 + rr);
                    ins3k(packkey(acc[mi][nj][rr], idx), k0, k1, k2);
                }
            }
            // butterfly over tg (lanes ^16, ^32)
#pragma unroll
            for (int s = 16; s <= 32; s <<= 1) {
                unsigned b0 = (unsigned)__shfl_xor((int)k0, s, 64);
                unsigned b1 = (unsigned)__shfl_xor((int)k1, s, 64);
                unsigned b2 = (unsigned)__shfl_xor((int)k2, s, 64);
                merge3k(k0, k1, k2, b0, b1, b2);
            }
            if (tg == 0) {
                int col = wc * 128 + nj * 16 + tx;
                unsigned* e = &evt[col * 6 + wr * 3];
                e[0] = k0; e[1] = k1; e[2] = k2;
            }
        }
    }
    __syncthreads();

    if (t < BM) {
        unsigned k0 = 0, k1 = 0, k2 = 0;
        const unsigned* e = &evu[t * 25];
#pragma unroll
        for (int s = 0; s < 24; ++s) ins3k(e[s], k0, k1, k2);
        unsigned* pk = pkeys + (size_t)(rb + t) * ROWKEYS + Jb * 6;   // h=0
        pk[0] = k0; pk[1] = k1; pk[2] = k2;
    }
    if (do_tr) {
        unsigned k0 = 0, k1 = 0, k2 = 0;
        const unsigned* e = &evt[t * 6];
#pragma unroll
        for (int s = 0; s < 6; ++s) ins3k(e[s], k0, k1, k2);
        unsigned* pk = pkeys + (size_t)(jb + t) * ROWKEYS + (ib >> 1) * 6 + (ib & 1) * 3;
        pk[0] = k0; pk[1] = k1; pk[2] = k2;
    }
}

// --- Kernel 4: merge 192 keys -> top-8, exact fp64 re-rank + softmax + gather + out ---
// 4 rows per block (4 independent waves) for latency hiding on the gathers.
__global__ __launch_bounds__(256)
void rerank_out_kernel(const float* __restrict__ proj, const unsigned* __restrict__ pkeys,
                       const float* __restrict__ sess, float* __restrict__ out,
                       float* __restrict__ cos_out) {
    int r = blockIdx.x * 4 + (threadIdx.x >> 6);
    int t = threadIdx.x & 63;     // lane within wave
    unsigned bk[NCAND];
#pragma unroll
    for (int p = 0; p < NCAND; ++p) bk[p] = 0;
    const unsigned* pk = pkeys + (size_t)r * ROWKEYS;
    for (int s = 0; s < ROWKEYS; ++s) {
        unsigned key = pk[s];
        if (key > bk[NCAND - 1]) {
#pragma unroll
            for (int p = NCAND - 1; p > 0; --p)
                bk[p] = (key > bk[p]) ? ((key > bk[p - 1]) ? bk[p - 1] : key) : bk[p];
            bk[0] = key > bk[0] ? key : bk[0];
        }
    }
    int cj[NCAND];
#pragma unroll
    for (int i = 0; i < NCAND; ++i) cj[i] = 8191 - (int)(bk[i] & 0x1FFFu);

    const float* pr = proj + (size_t)r * DD;
    float myp[8];
#pragma unroll
    for (int k = 0; k < 8; ++k) myp[k] = pr[t * 8 + k];
    double part[NCAND];
#pragma unroll
    for (int i = 0; i < NCAND; ++i) {
        const float* pc = proj + (size_t)cj[i] * DD;
        double s = 0.0;
#pragma unroll
        for (int k = 0; k < 8; ++k) s += (double)myp[k] * (double)pc[t * 8 + k];
        part[i] = s;
    }
#pragma unroll
    for (int i = 0; i < NCAND; ++i) {
#pragma unroll
        for (int s = 1; s < 64; s <<= 1) part[i] += __shfl_xor(part[i], s, 64);
    }
    double bv0 = -1e300, bv1 = -1e300, bv2 = -1e300;
    int bj0 = 0x7fffffff, bj1 = 0x7fffffff, bj2 = 0x7fffffff;
#pragma unroll
    for (int i = 0; i < NCAND; ++i) {
        double v = part[i]; int j = cj[i];
        bool g2 = (v > bv2) || (v == bv2 && j < bj2);
        bool g1 = (v > bv1) || (v == bv1 && j < bj1);
        bool g0 = (v > bv0) || (v == bv0 && j < bj0);
        if (g2) {
            if (g1) {
                if (g0) { bv2 = bv1; bj2 = bj1; bv1 = bv0; bj1 = bj0; bv0 = v; bj0 = j; }
                else    { bv2 = bv1; bj2 = bj1; bv1 = v; bj1 = j; }
            } else      { bv2 = v; bj2 = j; }
        }
    }
    double e1 = exp(bv1 - bv0), e2 = exp(bv2 - bv0);
    double inv = 1.0 / (1.0 + e1 + e2);
    float w0 = (float)inv, w1 = (float)(e1 * inv), w2 = (float)(e2 * inv);
    if (t == 0) {
        cos_out[r * 3 + 0] = w0; cos_out[r * 3 + 1] = w1; cos_out[r * 3 + 2] = w2;
    }
    const float4* s0 = (const float4*)(sess + (size_t)bj0 * DD);
    const float4* s1 = (const float4*)(sess + (size_t)bj1 * DD);
    const float4* s2 = (const float4*)(sess + (size_t)bj2 * DD);
    float4* o = (float4*)(out + (size_t)r * 3 * DD);
    float4* nb = (float4*)(out + (size_t)NB * 3 * DD + (size_t)r * DD);
#pragma unroll
    for (int e = 0; e < 2; ++e) {
        int q = t + e * 64;
        float4 x0 = s0[q], x1 = s1[q], x2 = s2[q];
        o[q] = x0; o[128 + q] = x1; o[256 + q] = x2;
        float4 v;
        v.x = fmaf(w0, x0.x, fmaf(w1, x1.x, w2 * x2.x));
        v.y = fmaf(w0, x0.y, fmaf(w1, x1.y, w2 * x2.y));
        v.z = fmaf(w0, x0.z, fmaf(w1, x1.z, w2 * x2.z));
        v.w = fmaf(w0, x0.w, fmaf(w1, x1.w, w2 * x2.w));
        nb[q] = v;
    }
}

extern "C" void kernel_launch(void* const* d_in, const int* in_sizes, int n_in,
                              void* d_out, int out_size, void* d_ws, size_t ws_size,
                              hipStream_t stream) {
    const float* sess = (const float*)d_in[0];
    // d_in[1] = pool_emb: unused by the reference
    const float* W1 = (const float*)d_in[2];
    const float* b1 = (const float*)d_in[3];
    const float* W2 = (const float*)d_in[4];
    const float* b2 = (const float*)d_in[5];
    float* out = (float*)d_out;

    const size_t MBc = 1u << 20;
    char* W = (char*)d_ws;
    // [0,16MB): sess_hi+sess_lo during prep/gemm1; proj f32 afterwards (stream-serialized)
    float*   proj    = (float*)W;
    ushortT* sess_hi = (ushortT*)W;
    ushortT* sess_lo = sess_hi + (size_t)NB * DD;
    ushortT* projb   = (ushortT*)(W + 16 * MBc);          // 8 MB
    ushortT* h_hi    = (ushortT*)(W + 24 * MBc);          // 4 MB (dead after gemm2)
    ushortT* h_lo    = (ushortT*)(W + 28 * MBc);          // 4 MB (dead after gemm2)
    ushortT* w1t_hi  = (ushortT*)(W + 32 * MBc);
    ushortT* w1t_lo  = w1t_hi + 256 * 512;
    ushortT* w2t_hi  = w1t_lo + 256 * 512;
    ushortT* w2t_lo  = w2t_hi + 512 * 256;
    unsigned* pkeys  = (unsigned*)(W + 24 * MBc);         // overlays h_hi/h_lo: 6.3 MB

    float* cos_out = out + (size_t)NB * 3 * DD + (size_t)NB * DD;

    hipLaunchKernelGGL(prep_kernel, dim3(2176), dim3(256), 0, stream,
                       sess, W1, W2, sess_hi, sess_lo, w1t_hi, w1t_lo, w2t_hi, w2t_lo);
    hipLaunchKernelGGL((mlp_gemm<512, 256, 0>), dim3(NB / 64, 1), dim3(256), 0, stream,
                       sess_hi, sess_lo, w1t_hi, w1t_lo, b1, h_hi, h_lo, (float*)nullptr, (ushortT*)nullptr);
    hipLaunchKernelGGL((mlp_gemm<256, 512, 1>), dim3(NB / 64, 2), dim3(256), 0, stream,
                       h_hi, h_lo, w2t_hi, w2t_lo, b2, (ushortT*)nullptr, (ushortT*)nullptr, proj, projb);
    hipMemsetAsync(pkeys, 0, (size_t)NB * ROWKEYS * sizeof(unsigned), stream);
    hipLaunchKernelGGL(sim_mfma_kernel, dim3(NB / BM, NB / BN), dim3(256), 0, stream,
                       (const short*)projb, pkeys);
    hipLaunchKernelGGL(rerank_out_kernel, dim3(NB / 4), dim3(256), 0, stream,
                       proj, pkeys, sess, out, cos_out);
}

// Round 9
// 198.196 us; speedup vs baseline: 1.1864x; 1.1864x over previous
//
#include <hip/hip_runtime.h>
#include <hip/hip_bf16.h>
#include <math.h>

#define NB 8192
#define DD 512
#define HH 256
#define TB 128             // sim tile 128x128
#define BK 32
#define KT (DD / BK)       // 16 k-tiles
#define NSLOT 64           // slots per row (one per 128-col tile)
#define ROWKEYS (NSLOT * 3)   // 192 keys per row
#define NCAND 8

typedef unsigned short ushortT;
typedef __attribute__((ext_vector_type(8))) short bf16x8;
typedef __attribute__((ext_vector_type(4))) float f32x4;

#define AS1(p) ((const __attribute__((address_space(1))) void*)(p))
#define AS3(p) ((__attribute__((address_space(3))) void*)(p))

__device__ __forceinline__ ushortT bf16rne(float f) {
    unsigned u = __float_as_uint(f);
    unsigned r = u + 0x7FFFu + ((u >> 16) & 1u);
    return (ushortT)(r >> 16);
}
__device__ __forceinline__ float bf16tof(ushortT h) {
    return __uint_as_float(((unsigned)h) << 16);
}

// ---------------- Kernel 0: prep — split sess to bf16 hi/lo; transpose+split W1,W2 ----------------
__global__ __launch_bounds__(256)
void prep_kernel(const float* __restrict__ sess, const float* __restrict__ W1,
                 const float* __restrict__ W2,
                 ushortT* __restrict__ sess_hi, ushortT* __restrict__ sess_lo,
                 ushortT* __restrict__ w1t_hi, ushortT* __restrict__ w1t_lo,
                 ushortT* __restrict__ w2t_hi, ushortT* __restrict__ w2t_lo) {
    const int b = blockIdx.x, t = threadIdx.x;
    if (b < 2048) {
        size_t i = (size_t)b * 2048 + t * 8;
        float4 f0 = *(const float4*)&sess[i];
        float4 f1 = *(const float4*)&sess[i + 4];
        float f[8] = {f0.x, f0.y, f0.z, f0.w, f1.x, f1.y, f1.z, f1.w};
        unsigned hp[4], lp[4];
#pragma unroll
        for (int j = 0; j < 4; ++j) {
            ushortT h0 = bf16rne(f[2 * j]), h1 = bf16rne(f[2 * j + 1]);
            ushortT l0 = bf16rne(f[2 * j] - bf16tof(h0));
            ushortT l1 = bf16rne(f[2 * j + 1] - bf16tof(h1));
            hp[j] = (unsigned)h0 | ((unsigned)h1 << 16);
            lp[j] = (unsigned)l0 | ((unsigned)l1 << 16);
        }
        *(uint4*)&sess_hi[i] = *(uint4*)hp;
        *(uint4*)&sess_lo[i] = *(uint4*)lp;
    } else if (b < 2112) {
        int o = (b - 2048) * 2048 + t * 8;
        int k = o >> 8, c = o & 255;
        float4 f0 = *(const float4*)&W1[(size_t)k * 256 + c];
        float4 f1 = *(const float4*)&W1[(size_t)k * 256 + c + 4];
        float f[8] = {f0.x, f0.y, f0.z, f0.w, f1.x, f1.y, f1.z, f1.w};
#pragma unroll
        for (int j = 0; j < 8; ++j) {
            ushortT h = bf16rne(f[j]);
            w1t_hi[(size_t)(c + j) * 512 + k] = h;
            w1t_lo[(size_t)(c + j) * 512 + k] = bf16rne(f[j] - bf16tof(h));
        }
    } else {
        int o = (b - 2112) * 2048 + t * 8;
        int k = o >> 9, c = o & 511;
        float4 f0 = *(const float4*)&W2[(size_t)k * 512 + c];
        float4 f1 = *(const float4*)&W2[(size_t)k * 512 + c + 4];
        float f[8] = {f0.x, f0.y, f0.z, f0.w, f1.x, f1.y, f1.z, f1.w};
#pragma unroll
        for (int j = 0; j < 8; ++j) {
            ushortT h = bf16rne(f[j]);
            w2t_hi[(size_t)(c + j) * 256 + k] = h;
            w2t_lo[(size_t)(c + j) * 256 + k] = bf16rne(f[j] - bf16tof(h));
        }
    }
}

// -------- Kernel 1/2: split-bf16 MFMA GEMM, C = A @ B^T (+bias), 64x256 tile --------
template <int KDIM, int NOUT, int EPI>
__global__ __launch_bounds__(256)
void mlp_gemm(const ushortT* __restrict__ Ahi, const ushortT* __restrict__ Alo,
              const ushortT* __restrict__ Bhi, const ushortT* __restrict__ Blo,
              const float* __restrict__ bias,
              ushortT* __restrict__ Ohi, ushortT* __restrict__ Olo,
              float* __restrict__ Of, ushortT* __restrict__ Ob) {
    __shared__ short gsmem[2 * 20480];
    const int KTILES = KDIM / BK;
    const int t = threadIdx.x;
    const int w = t >> 6, l = t & 63;
    const int wr = w >> 1, wc = w & 1;
    const int tx = l & 15, tg = l >> 4;
    const int rb = blockIdx.x * 64;
    const int cb = blockIdx.y * 256;

    const int rin = l >> 2;
    const int tgs = (l & 3) ^ ((rin >> 1) & 3);
    const int loff = tx * BK + ((tg ^ ((tx >> 1) & 3)) << 3);

    f32x4 acc[2][8];
#pragma unroll
    for (int i = 0; i < 2; ++i)
#pragma unroll
        for (int j = 0; j < 8; ++j) acc[i][j] = (f32x4){0.f, 0.f, 0.f, 0.f};

#define GSTAGE(buf, k0v)                                                                     \
    {                                                                                        \
        _Pragma("unroll")                                                                    \
        for (int q = 0; q < 10; ++q) {                                                       \
            int c = w * 10 + q;                                                              \
            const ushortT* src; int row; int lofs;                                           \
            if (c < 4)       { src = Ahi; row = rb + c * 16 + rin;        lofs = 0     + c * 512; }        \
            else if (c < 8)  { src = Alo; row = rb + (c - 4) * 16 + rin;  lofs = 2048  + (c - 4) * 512; }  \
            else if (c < 24) { src = Bhi; row = cb + (c - 8) * 16 + rin;  lofs = 4096  + (c - 8) * 512; }  \
            else             { src = Blo; row = cb + (c - 24) * 16 + rin; lofs = 12288 + (c - 24) * 512; } \
            const ushortT* g = src + (size_t)row * KDIM + (k0v) + tgs * 8;                   \
            __builtin_amdgcn_global_load_lds(AS1(g), AS3(gsmem + (buf) * 20480 + lofs + l * 8), 16, 0, 0); \
        }                                                                                    \
    }

#define GCOMPUTE(kt)                                                                         \
    {                                                                                        \
        const short* Bu = gsmem + ((kt) & 1) * 20480;                                        \
        bf16x8 ah[2], al[2], bh[8], bl[8];                                                   \
        _Pragma("unroll")                                                                    \
        for (int mi = 0; mi < 2; ++mi) {                                                     \
            ah[mi] = *(const bf16x8*)&Bu[0 + (wr * 2 + mi) * 512 + loff];                    \
            al[mi] = *(const bf16x8*)&Bu[2048 + (wr * 2 + mi) * 512 + loff];                 \
        }                                                                                    \
        _Pragma("unroll")                                                                    \
        for (int nj = 0; nj < 8; ++nj) {                                                     \
            bh[nj] = *(const bf16x8*)&Bu[4096 + (wc * 8 + nj) * 512 + loff];                 \
            bl[nj] = *(const bf16x8*)&Bu[12288 + (wc * 8 + nj) * 512 + loff];                \
        }                                                                                    \
        asm volatile("s_waitcnt lgkmcnt(0)" ::: "memory");                                   \
        __builtin_amdgcn_sched_barrier(0);                                                   \
        __builtin_amdgcn_s_barrier();                                                        \
        __builtin_amdgcn_sched_barrier(0);                                                   \
        _Pragma("unroll")                                                                    \
        for (int mi = 0; mi < 2; ++mi)                                                       \
            _Pragma("unroll")                                                                \
            for (int nj = 0; nj < 8; ++nj) {                                                 \
                acc[mi][nj] = __builtin_amdgcn_mfma_f32_16x16x32_bf16(ah[mi], bh[nj], acc[mi][nj], 0, 0, 0); \
                acc[mi][nj] = __builtin_amdgcn_mfma_f32_16x16x32_bf16(ah[mi], bl[nj], acc[mi][nj], 0, 0, 0); \
                acc[mi][nj] = __builtin_amdgcn_mfma_f32_16x16x32_bf16(al[mi], bh[nj], acc[mi][nj], 0, 0, 0); \
            }                                                                                \
    }

    GSTAGE(0, 0);
    for (int kt = 0; kt < KTILES - 1; ++kt) {
        GSTAGE((kt + 1) & 1, (kt + 1) * BK);
        asm volatile("s_waitcnt vmcnt(10)" ::: "memory");
        __builtin_amdgcn_sched_barrier(0);
        __builtin_amdgcn_s_barrier();
        __builtin_amdgcn_sched_barrier(0);
        GCOMPUTE(kt);
    }
    asm volatile("s_waitcnt vmcnt(0)" ::: "memory");
    __builtin_amdgcn_sched_barrier(0);
    __builtin_amdgcn_s_barrier();
    __builtin_amdgcn_sched_barrier(0);
    GCOMPUTE(KTILES - 1);
#undef GSTAGE
#undef GCOMPUTE

#pragma unroll
    for (int mi = 0; mi < 2; ++mi) {
#pragma unroll
        for (int nj = 0; nj < 8; ++nj) {
            int col = cb + wc * 128 + nj * 16 + tx;
            float bv = bias[col];
#pragma unroll
            for (int rr = 0; rr < 4; ++rr) {
                int row = rb + wr * 32 + mi * 16 + tg * 4 + rr;
                float v = acc[mi][nj][rr] + bv;
                if (EPI == 0) {
                    v = fmaxf(v, 0.f);
                    ushortT h = bf16rne(v);
                    Ohi[(size_t)row * NOUT + col] = h;
                    Olo[(size_t)row * NOUT + col] = bf16rne(v - bf16tof(h));
                } else {
                    Of[(size_t)row * NOUT + col] = v;
                    Ob[(size_t)row * NOUT + col] = bf16rne(v);
                }
            }
        }
    }
}

// ---- packed-key top-3 helpers (u32 key = monotone(f32)&~0x1FFF | (8191-idx)) ----
__device__ __forceinline__ void ins3k(unsigned key, unsigned& k0, unsigned& k1, unsigned& k2) {
    bool g0 = key > k0, g1 = key > k1, g2 = key > k2;
    k2 = g1 ? k1 : (g2 ? key : k2);
    k1 = g0 ? k0 : (g1 ? key : k1);
    k0 = g0 ? key : k0;
}
__device__ __forceinline__ void merge3k(unsigned& a0, unsigned& a1, unsigned& a2,
                                        unsigned b0, unsigned b1, unsigned b2) {
    unsigned m0 = a0 > b0 ? a0 : b0;
    bool c0 = a0 > b0;
    unsigned ca1 = c0 ? a1 : b1;
    unsigned cb0 = c0 ? b0 : a0;
    unsigned ca2 = c0 ? a2 : b2;
    unsigned cb1 = c0 ? b1 : a1;
    bool c1 = ca1 > cb0;
    unsigned m1 = c1 ? ca1 : cb0;
    unsigned x = c1 ? ca2 : ca1;
    unsigned y = c1 ? cb0 : cb1;
    unsigned m2 = x > y ? x : y;
    a0 = m0; a1 = m1; a2 = m2;
}
__device__ __forceinline__ unsigned packkey(float f, unsigned idx) {
    unsigned u = __float_as_uint(f);
    unsigned tt = (unsigned)((int)u >> 31) | 0x80000000u;
    return ((u ^ tt) & 0xFFFFE000u) | (8191u - idx);
}

// ------- Kernel 3: symmetric bf16 MFMA sim, 128x128 tiles, upper triangle (i<=j) -------
// Direct epilogue -> pkeys[row][j]; strictly-upper blocks also emit per-col top-3
// -> pkeys[col][i]. Slots 0..d-1 transposed, d..63 direct: exact cover, no memset.
__global__ __launch_bounds__(256)
void sim_mfma_kernel(const short* __restrict__ projb, unsigned* __restrict__ pkeys) {
    const int ib = blockIdx.x, jbk = blockIdx.y;
    if (ib > jbk) return;
    const bool do_tr = (ib < jbk);

    __shared__ short smem[2 * TB * BK * 2];   // 32 KB: As[2][128*32], Bs[2][128*32]
    short* As = smem;
    short* Bs = smem + 2 * TB * BK;
    unsigned* evu = (unsigned*)smem;          // direct overlay [128][25]
    unsigned* evt = (unsigned*)smem + 3200;   // transposed overlay [128][6]

    const int t = threadIdx.x;
    const int w = t >> 6, l = t & 63;
    const int wr = w >> 1, wc = w & 1;
    const int tx = l & 15, tg = l >> 4;
    const int rb = ib * TB;
    const int jb = jbk * TB;

    const int rin = l >> 2;
    const int tgs = (l & 3) ^ ((rin >> 1) & 3);
    const int loff = tx * BK + ((tg ^ ((tx >> 1) & 3)) << 3);

    f32x4 acc[4][4];
#pragma unroll
    for (int i = 0; i < 4; ++i)
#pragma unroll
        for (int j = 0; j < 4; ++j) acc[i][j] = (f32x4){0.f, 0.f, 0.f, 0.f};

    // 4 loads/thread per K-step: 2 A-chunks + 2 B-chunks (8 chunks of 16 rows each)
#define STAGE(buf, k0)                                                                      \
    {                                                                                       \
        _Pragma("unroll")                                                                   \
        for (int q = 0; q < 2; ++q) {                                                       \
            int c = w * 2 + q;                                                              \
            const short* ga = projb + (size_t)(rb + c * 16 + rin) * DD + (k0) + tgs * 8;    \
            __builtin_amdgcn_global_load_lds(AS1(ga), AS3(As + (buf) * (TB * BK) + c * 512 + l * 8), 16, 0, 0); \
            const short* gb = projb + (size_t)(jb + c * 16 + rin) * DD + (k0) + tgs * 8;    \
            __builtin_amdgcn_global_load_lds(AS1(gb), AS3(Bs + (buf) * (TB * BK) + c * 512 + l * 8), 16, 0, 0); \
        }                                                                                   \
    }

#define COMPUTE(kt)                                                                          \
    {                                                                                        \
        const short* Ab = As + ((kt) & 1) * (TB * BK);                                       \
        const short* Bb = Bs + ((kt) & 1) * (TB * BK);                                       \
        bf16x8 af[4], bfr[4];                                                                \
        _Pragma("unroll")                                                                    \
        for (int mi = 0; mi < 4; ++mi)                                                       \
            af[mi] = *(const bf16x8*)&Ab[(wr * 64 + mi * 16) * BK + loff];                   \
        _Pragma("unroll")                                                                    \
        for (int nj = 0; nj < 4; ++nj)                                                       \
            bfr[nj] = *(const bf16x8*)&Bb[(wc * 64 + nj * 16) * BK + loff];                  \
        asm volatile("s_waitcnt lgkmcnt(0)" ::: "memory");                                   \
        __builtin_amdgcn_sched_barrier(0);                                                   \
        __builtin_amdgcn_s_barrier();                                                        \
        __builtin_amdgcn_sched_barrier(0);                                                   \
        _Pragma("unroll")                                                                    \
        for (int mi = 0; mi < 4; ++mi)                                                       \
            _Pragma("unroll")                                                                \
            for (int nj = 0; nj < 4; ++nj)                                                   \
                acc[mi][nj] = __builtin_amdgcn_mfma_f32_16x16x32_bf16(af[mi], bfr[nj], acc[mi][nj], 0, 0, 0); \
    }

    STAGE(0, 0);
    for (int kt = 0; kt < KT - 1; ++kt) {
        STAGE((kt + 1) & 1, (kt + 1) * BK);
        asm volatile("s_waitcnt vmcnt(4)" ::: "memory");
        __builtin_amdgcn_sched_barrier(0);
        __builtin_amdgcn_s_barrier();
        __builtin_amdgcn_sched_barrier(0);
        COMPUTE(kt);
    }
    asm volatile("s_waitcnt vmcnt(0)" ::: "memory");
    __builtin_amdgcn_sched_barrier(0);
    __builtin_amdgcn_s_barrier();
    __builtin_amdgcn_sched_barrier(0);
    COMPUTE(KT - 1);
#undef STAGE
#undef COMPUTE

    __syncthreads();   // K-loop done everywhere before LDS overlay

    // ---- direct epilogue: per-row top3 over this block's 128 cols ----
    unsigned cinv[4];
#pragma unroll
    for (int nj = 0; nj < 4; ++nj)
        cinv[nj] = 8191u - (unsigned)(jb + wc * 64 + nj * 16 + tx);
#pragma unroll
    for (int mi = 0; mi < 4; ++mi) {
#pragma unroll
        for (int rr = 0; rr < 4; ++rr) {
            unsigned k0 = 0, k1 = 0, k2 = 0;
#pragma unroll
            for (int nj = 0; nj < 4; ++nj) {
                unsigned u = __float_as_uint(acc[mi][nj][rr]);
                unsigned tt = (unsigned)((int)u >> 31) | 0x80000000u;
                ins3k(((u ^ tt) & 0xFFFFE000u) | cinv[nj], k0, k1, k2);
            }
#pragma unroll
            for (int s = 1; s <= 2; s <<= 1) {
                unsigned b0 = (unsigned)__shfl_xor((int)k0, s, 64);
                unsigned b1 = (unsigned)__shfl_xor((int)k1, s, 64);
                unsigned b2 = (unsigned)__shfl_xor((int)k2, s, 64);
                merge3k(k0, k1, k2, b0, b1, b2);
            }
            if ((tx & 3) == 0) {
                int lrow = wr * 64 + mi * 16 + tg * 4 + rr;
                unsigned* e = &evu[lrow * 25 + (wc * 4 + (tx >> 2)) * 3];
                e[0] = k0; e[1] = k1; e[2] = k2;
            }
        }
    }

    // ---- transposed epilogue (strictly-upper): per-col top3 over this block's 128 rows ----
    if (do_tr) {
#pragma unroll
        for (int nj = 0; nj < 4; ++nj) {
            unsigned k0 = 0, k1 = 0, k2 = 0;
#pragma unroll
            for (int mi = 0; mi < 4; ++mi) {
#pragma unroll
                for (int rr = 0; rr < 4; ++rr) {
                    unsigned idx = (unsigned)(rb + wr * 64 + mi * 16 + tg * 4 + rr);
                    ins3k(packkey(acc[mi][nj][rr], idx), k0, k1, k2);
                }
            }
#pragma unroll
            for (int s = 16; s <= 32; s <<= 1) {
                unsigned b0 = (unsigned)__shfl_xor((int)k0, s, 64);
                unsigned b1 = (unsigned)__shfl_xor((int)k1, s, 64);
                unsigned b2 = (unsigned)__shfl_xor((int)k2, s, 64);
                merge3k(k0, k1, k2, b0, b1, b2);
            }
            if (tg == 0) {
                int col = wc * 64 + nj * 16 + tx;
                unsigned* e = &evt[col * 6 + wr * 3];
                e[0] = k0; e[1] = k1; e[2] = k2;
            }
        }
    }
    __syncthreads();

    if (t < TB) {
        unsigned k0 = 0, k1 = 0, k2 = 0;
        const unsigned* e = &evu[t * 25];
#pragma unroll
        for (int s = 0; s < 24; ++s) ins3k(e[s], k0, k1, k2);
        unsigned* pk = pkeys + (size_t)(rb + t) * ROWKEYS + jbk * 3;
        pk[0] = k0; pk[1] = k1; pk[2] = k2;
    }
    if (do_tr && t < TB) {
        unsigned k0 = 0, k1 = 0, k2 = 0;
        const unsigned* e = &evt[t * 6];
#pragma unroll
        for (int s = 0; s < 6; ++s) ins3k(e[s], k0, k1, k2);
        unsigned* pk = pkeys + (size_t)(jb + t) * ROWKEYS + ib * 3;
        pk[0] = k0; pk[1] = k1; pk[2] = k2;
    }
}

// --- Kernel 4: merge 192 keys -> top-8, exact fp64 re-rank + softmax + gather + out ---
__global__ __launch_bounds__(256)
void rerank_out_kernel(const float* __restrict__ proj, const unsigned* __restrict__ pkeys,
                       const float* __restrict__ sess, float* __restrict__ out,
                       float* __restrict__ cos_out) {
    int r = blockIdx.x * 4 + (threadIdx.x >> 6);
    int t = threadIdx.x & 63;
    unsigned bk[NCAND];
#pragma unroll
    for (int p = 0; p < NCAND; ++p) bk[p] = 0;
    const unsigned* pk = pkeys + (size_t)r * ROWKEYS;
    for (int s = 0; s < ROWKEYS; ++s) {
        unsigned key = pk[s];
        if (key > bk[NCAND - 1]) {
#pragma unroll
            for (int p = NCAND - 1; p > 0; --p)
                bk[p] = (key > bk[p]) ? ((key > bk[p - 1]) ? bk[p - 1] : key) : bk[p];
            bk[0] = key > bk[0] ? key : bk[0];
        }
    }
    int cj[NCAND];
#pragma unroll
    for (int i = 0; i < NCAND; ++i) cj[i] = 8191 - (int)(bk[i] & 0x1FFFu);

    const float* pr = proj + (size_t)r * DD;
    float myp[8];
#pragma unroll
    for (int k = 0; k < 8; ++k) myp[k] = pr[t * 8 + k];
    double part[NCAND];
#pragma unroll
    for (int i = 0; i < NCAND; ++i) {
        const float* pc = proj + (size_t)cj[i] * DD;
        double s = 0.0;
#pragma unroll
        for (int k = 0; k < 8; ++k) s += (double)myp[k] * (double)pc[t * 8 + k];
        part[i] = s;
    }
#pragma unroll
    for (int i = 0; i < NCAND; ++i) {
#pragma unroll
        for (int s = 1; s < 64; s <<= 1) part[i] += __shfl_xor(part[i], s, 64);
    }
    double bv0 = -1e300, bv1 = -1e300, bv2 = -1e300;
    int bj0 = 0x7fffffff, bj1 = 0x7fffffff, bj2 = 0x7fffffff;
#pragma unroll
    for (int i = 0; i < NCAND; ++i) {
        double v = part[i]; int j = cj[i];
        bool g2 = (v > bv2) || (v == bv2 && j < bj2);
        bool g1 = (v > bv1) || (v == bv1 && j < bj1);
        bool g0 = (v > bv0) || (v == bv0 && j < bj0);
        if (g2) {
            if (g1) {
                if (g0) { bv2 = bv1; bj2 = bj1; bv1 = bv0; bj1 = bj0; bv0 = v; bj0 = j; }
                else    { bv2 = bv1; bj2 = bj1; bv1 = v; bj1 = j; }
            } else      { bv2 = v; bj2 = j; }
        }
    }
    double e1 = exp(bv1 - bv0), e2 = exp(bv2 - bv0);
    double inv = 1.0 / (1.0 + e1 + e2);
    float w0 = (float)inv, w1 = (float)(e1 * inv), w2 = (float)(e2 * inv);
    if (t == 0) {
        cos_out[r * 3 + 0] = w0; cos_out[r * 3 + 1] = w1; cos_out[r * 3 + 2] = w2;
    }
    const float4* s0 = (const float4*)(sess + (size_t)bj0 * DD);
    const float4* s1 = (const float4*)(sess + (size_t)bj1 * DD);
    const float4* s2 = (const float4*)(sess + (size_t)bj2 * DD);
    float4* o = (float4*)(out + (size_t)r * 3 * DD);
    float4* nb = (float4*)(out + (size_t)NB * 3 * DD + (size_t)r * DD);
#pragma unroll
    for (int e = 0; e < 2; ++e) {
        int q = t + e * 64;
        float4 x0 = s0[q], x1 = s1[q], x2 = s2[q];
        o[q] = x0; o[128 + q] = x1; o[256 + q] = x2;
        float4 v;
        v.x = fmaf(w0, x0.x, fmaf(w1, x1.x, w2 * x2.x));
        v.y = fmaf(w0, x0.y, fmaf(w1, x1.y, w2 * x2.y));
        v.z = fmaf(w0, x0.z, fmaf(w1, x1.z, w2 * x2.z));
        v.w = fmaf(w0, x0.w, fmaf(w1, x1.w, w2 * x2.w));
        nb[q] = v;
    }
}

extern "C" void kernel_launch(void* const* d_in, const int* in_sizes, int n_in,
                              void* d_out, int out_size, void* d_ws, size_t ws_size,
                              hipStream_t stream) {
    const float* sess = (const float*)d_in[0];
    // d_in[1] = pool_emb: unused by the reference
    const float* W1 = (const float*)d_in[2];
    const float* b1 = (const float*)d_in[3];
    const float* W2 = (const float*)d_in[4];
    const float* b2 = (const float*)d_in[5];
    float* out = (float*)d_out;

    const size_t MBc = 1u << 20;
    char* W = (char*)d_ws;
    // [0,16MB): sess_hi+sess_lo during prep/gemm1; proj f32 afterwards (stream-serialized)
    float*   proj    = (float*)W;
    ushortT* sess_hi = (ushortT*)W;
    ushortT* sess_lo = sess_hi + (size_t)NB * DD;
    ushortT* projb   = (ushortT*)(W + 16 * MBc);          // 8 MB
    ushortT* h_hi    = (ushortT*)(W + 24 * MBc);          // 4 MB (dead after gemm2)
    ushortT* h_lo    = (ushortT*)(W + 28 * MBc);          // 4 MB (dead after gemm2)
    ushortT* w1t_hi  = (ushortT*)(W + 32 * MBc);
    ushortT* w1t_lo  = w1t_hi + 256 * 512;
    ushortT* w2t_hi  = w1t_lo + 256 * 512;
    ushortT* w2t_lo  = w2t_hi + 512 * 256;
    unsigned* pkeys  = (unsigned*)(W + 24 * MBc);         // overlays h_hi/h_lo: 6.3 MB

    float* cos_out = out + (size_t)NB * 3 * DD + (size_t)NB * DD;

    hipLaunchKernelGGL(prep_kernel, dim3(2176), dim3(256), 0, stream,
                       sess, W1, W2, sess_hi, sess_lo, w1t_hi, w1t_lo, w2t_hi, w2t_lo);
    hipLaunchKernelGGL((mlp_gemm<512, 256, 0>), dim3(NB / 64, 1), dim3(256), 0, stream,
                       sess_hi, sess_lo, w1t_hi, w1t_lo, b1, h_hi, h_lo, (float*)nullptr, (ushortT*)nullptr);
    hipLaunchKernelGGL((mlp_gemm<256, 512, 1>), dim3(NB / 64, 2), dim3(256), 0, stream,
                       h_hi, h_lo, w2t_hi, w2t_lo, b2, (ushortT*)nullptr, (ushortT*)nullptr, proj, projb);
    hipLaunchKernelGGL(sim_mfma_kernel, dim3(NB / TB, NB / TB), dim3(256), 0, stream,
                       (const short*)projb, pkeys);
    hipLaunchKernelGGL(rerank_out_kernel, dim3(NB / 4), dim3(256), 0, stream,
                       proj, pkeys, sess, out, cos_out);
}

// Round 10
// 149.614 us; speedup vs baseline: 1.5717x; 1.3247x over previous
//
#include <hip/hip_runtime.h>
#include <hip/hip_bf16.h>
#include <math.h>

#define NB 8192
#define DD 512
#define HH 256
#define TB 128             // sim tile 128x128
#define BK 32
#define KT (DD / BK)       // 16 k-tiles
#define NSLOT 64           // slots per row (one per 128-col tile)
#define ROWKEYS (NSLOT * 3)   // 192 keys per row
#define NCAND 8
#define NTRI 2080          // 64*65/2 triangle blocks

typedef unsigned short ushortT;
typedef __attribute__((ext_vector_type(8))) short bf16x8;
typedef __attribute__((ext_vector_type(4))) float f32x4;

#define AS1(p) ((const __attribute__((address_space(1))) void*)(p))
#define AS3(p) ((__attribute__((address_space(3))) void*)(p))

__device__ __forceinline__ ushortT bf16rne(float f) {
    unsigned u = __float_as_uint(f);
    unsigned r = u + 0x7FFFu + ((u >> 16) & 1u);
    return (ushortT)(r >> 16);
}
__device__ __forceinline__ float bf16tof(ushortT h) {
    return __uint_as_float(((unsigned)h) << 16);
}

// ---------------- Kernel 0: prep — split sess to bf16 hi/lo; transpose+split W1,W2 ----------------
__global__ __launch_bounds__(256)
void prep_kernel(const float* __restrict__ sess, const float* __restrict__ W1,
                 const float* __restrict__ W2,
                 ushortT* __restrict__ sess_hi, ushortT* __restrict__ sess_lo,
                 ushortT* __restrict__ w1t_hi, ushortT* __restrict__ w1t_lo,
                 ushortT* __restrict__ w2t_hi, ushortT* __restrict__ w2t_lo) {
    const int b = blockIdx.x, t = threadIdx.x;
    if (b < 2048) {
        size_t i = (size_t)b * 2048 + t * 8;
        float4 f0 = *(const float4*)&sess[i];
        float4 f1 = *(const float4*)&sess[i + 4];
        float f[8] = {f0.x, f0.y, f0.z, f0.w, f1.x, f1.y, f1.z, f1.w};
        unsigned hp[4], lp[4];
#pragma unroll
        for (int j = 0; j < 4; ++j) {
            ushortT h0 = bf16rne(f[2 * j]), h1 = bf16rne(f[2 * j + 1]);
            ushortT l0 = bf16rne(f[2 * j] - bf16tof(h0));
            ushortT l1 = bf16rne(f[2 * j + 1] - bf16tof(h1));
            hp[j] = (unsigned)h0 | ((unsigned)h1 << 16);
            lp[j] = (unsigned)l0 | ((unsigned)l1 << 16);
        }
        *(uint4*)&sess_hi[i] = *(uint4*)hp;
        *(uint4*)&sess_lo[i] = *(uint4*)lp;
    } else if (b < 2112) {
        int o = (b - 2048) * 2048 + t * 8;
        int k = o >> 8, c = o & 255;
        float4 f0 = *(const float4*)&W1[(size_t)k * 256 + c];
        float4 f1 = *(const float4*)&W1[(size_t)k * 256 + c + 4];
        float f[8] = {f0.x, f0.y, f0.z, f0.w, f1.x, f1.y, f1.z, f1.w};
#pragma unroll
        for (int j = 0; j < 8; ++j) {
            ushortT h = bf16rne(f[j]);
            w1t_hi[(size_t)(c + j) * 512 + k] = h;
            w1t_lo[(size_t)(c + j) * 512 + k] = bf16rne(f[j] - bf16tof(h));
        }
    } else {
        int o = (b - 2112) * 2048 + t * 8;
        int k = o >> 9, c = o & 511;
        float4 f0 = *(const float4*)&W2[(size_t)k * 512 + c];
        float4 f1 = *(const float4*)&W2[(size_t)k * 512 + c + 4];
        float f[8] = {f0.x, f0.y, f0.z, f0.w, f1.x, f1.y, f1.z, f1.w};
#pragma unroll
        for (int j = 0; j < 8; ++j) {
            ushortT h = bf16rne(f[j]);
            w2t_hi[(size_t)(c + j) * 256 + k] = h;
            w2t_lo[(size_t)(c + j) * 256 + k] = bf16rne(f[j] - bf16tof(h));
        }
    }
}

// -------- Kernel 1/2: split-bf16 MFMA GEMM, C = A @ B^T (+bias), 64x256 tile --------
template <int KDIM, int NOUT, int EPI>
__global__ __launch_bounds__(256)
void mlp_gemm(const ushortT* __restrict__ Ahi, const ushortT* __restrict__ Alo,
              const ushortT* __restrict__ Bhi, const ushortT* __restrict__ Blo,
              const float* __restrict__ bias,
              ushortT* __restrict__ Ohi, ushortT* __restrict__ Olo,
              float* __restrict__ Of, ushortT* __restrict__ Ob) {
    __shared__ short gsmem[2 * 20480];
    const int KTILES = KDIM / BK;
    const int t = threadIdx.x;
    const int w = t >> 6, l = t & 63;
    const int wr = w >> 1, wc = w & 1;
    const int tx = l & 15, tg = l >> 4;
    const int rb = blockIdx.x * 64;
    const int cb = blockIdx.y * 256;

    const int rin = l >> 2;
    const int tgs = (l & 3) ^ ((rin >> 1) & 3);
    const int loff = tx * BK + ((tg ^ ((tx >> 1) & 3)) << 3);

    f32x4 acc[2][8];
#pragma unroll
    for (int i = 0; i < 2; ++i)
#pragma unroll
        for (int j = 0; j < 8; ++j) acc[i][j] = (f32x4){0.f, 0.f, 0.f, 0.f};

#define GSTAGE(buf, k0v)                                                                     \
    {                                                                                        \
        _Pragma("unroll")                                                                    \
        for (int q = 0; q < 10; ++q) {                                                       \
            int c = w * 10 + q;                                                              \
            const ushortT* src; int row; int lofs;                                           \
            if (c < 4)       { src = Ahi; row = rb + c * 16 + rin;        lofs = 0     + c * 512; }        \
            else if (c < 8)  { src = Alo; row = rb + (c - 4) * 16 + rin;  lofs = 2048  + (c - 4) * 512; }  \
            else if (c < 24) { src = Bhi; row = cb + (c - 8) * 16 + rin;  lofs = 4096  + (c - 8) * 512; }  \
            else             { src = Blo; row = cb + (c - 24) * 16 + rin; lofs = 12288 + (c - 24) * 512; } \
            const ushortT* g = src + (size_t)row * KDIM + (k0v) + tgs * 8;                   \
            __builtin_amdgcn_global_load_lds(AS1(g), AS3(gsmem + (buf) * 20480 + lofs + l * 8), 16, 0, 0); \
        }                                                                                    \
    }

#define GCOMPUTE(kt)                                                                         \
    {                                                                                        \
        const short* Bu = gsmem + ((kt) & 1) * 20480;                                        \
        bf16x8 ah[2], al[2], bh[8], bl[8];                                                   \
        _Pragma("unroll")                                                                    \
        for (int mi = 0; mi < 2; ++mi) {                                                     \
            ah[mi] = *(const bf16x8*)&Bu[0 + (wr * 2 + mi) * 512 + loff];                    \
            al[mi] = *(const bf16x8*)&Bu[2048 + (wr * 2 + mi) * 512 + loff];                 \
        }                                                                                    \
        _Pragma("unroll")                                                                    \
        for (int nj = 0; nj < 8; ++nj) {                                                     \
            bh[nj] = *(const bf16x8*)&Bu[4096 + (wc * 8 + nj) * 512 + loff];                 \
            bl[nj] = *(const bf16x8*)&Bu[12288 + (wc * 8 + nj) * 512 + loff];                \
        }                                                                                    \
        asm volatile("s_waitcnt lgkmcnt(0)" ::: "memory");                                   \
        __builtin_amdgcn_sched_barrier(0);                                                   \
        __builtin_amdgcn_s_barrier();                                                        \
        __builtin_amdgcn_sched_barrier(0);                                                   \
        _Pragma("unroll")                                                                    \
        for (int mi = 0; mi < 2; ++mi)                                                       \
            _Pragma("unroll")                                                                \
            for (int nj = 0; nj < 8; ++nj) {                                                 \
                acc[mi][nj] = __builtin_amdgcn_mfma_f32_16x16x32_bf16(ah[mi], bh[nj], acc[mi][nj], 0, 0, 0); \
                acc[mi][nj] = __builtin_amdgcn_mfma_f32_16x16x32_bf16(ah[mi], bl[nj], acc[mi][nj], 0, 0, 0); \
                acc[mi][nj] = __builtin_amdgcn_mfma_f32_16x16x32_bf16(al[mi], bh[nj], acc[mi][nj], 0, 0, 0); \
            }                                                                                \
    }

    GSTAGE(0, 0);
    for (int kt = 0; kt < KTILES - 1; ++kt) {
        GSTAGE((kt + 1) & 1, (kt + 1) * BK);
        asm volatile("s_waitcnt vmcnt(10)" ::: "memory");
        __builtin_amdgcn_sched_barrier(0);
        __builtin_amdgcn_s_barrier();
        __builtin_amdgcn_sched_barrier(0);
        GCOMPUTE(kt);
    }
    asm volatile("s_waitcnt vmcnt(0)" ::: "memory");
    __builtin_amdgcn_sched_barrier(0);
    __builtin_amdgcn_s_barrier();
    __builtin_amdgcn_sched_barrier(0);
    GCOMPUTE(KTILES - 1);
#undef GSTAGE
#undef GCOMPUTE

#pragma unroll
    for (int mi = 0; mi < 2; ++mi) {
#pragma unroll
        for (int nj = 0; nj < 8; ++nj) {
            int col = cb + wc * 128 + nj * 16 + tx;
            float bv = bias[col];
#pragma unroll
            for (int rr = 0; rr < 4; ++rr) {
                int row = rb + wr * 32 + mi * 16 + tg * 4 + rr;
                float v = acc[mi][nj][rr] + bv;
                if (EPI == 0) {
                    v = fmaxf(v, 0.f);
                    ushortT h = bf16rne(v);
                    Ohi[(size_t)row * NOUT + col] = h;
                    Olo[(size_t)row * NOUT + col] = bf16rne(v - bf16tof(h));
                } else {
                    Of[(size_t)row * NOUT + col] = v;
                    Ob[(size_t)row * NOUT + col] = bf16rne(v);
                }
            }
        }
    }
}

// ---- packed-key top-3 helpers (u32 key = monotone(f32)&~0x1FFF | (8191-idx)) ----
__device__ __forceinline__ void ins3k(unsigned key, unsigned& k0, unsigned& k1, unsigned& k2) {
    bool g0 = key > k0, g1 = key > k1, g2 = key > k2;
    k2 = g1 ? k1 : (g2 ? key : k2);
    k1 = g0 ? k0 : (g1 ? key : k1);
    k0 = g0 ? key : k0;
}
__device__ __forceinline__ void merge3k(unsigned& a0, unsigned& a1, unsigned& a2,
                                        unsigned b0, unsigned b1, unsigned b2) {
    unsigned m0 = a0 > b0 ? a0 : b0;
    bool c0 = a0 > b0;
    unsigned ca1 = c0 ? a1 : b1;
    unsigned cb0 = c0 ? b0 : a0;
    unsigned ca2 = c0 ? a2 : b2;
    unsigned cb1 = c0 ? b1 : a1;
    bool c1 = ca1 > cb0;
    unsigned m1 = c1 ? ca1 : cb0;
    unsigned x = c1 ? ca2 : ca1;
    unsigned y = c1 ? cb0 : cb1;
    unsigned m2 = x > y ? x : y;
    a0 = m0; a1 = m1; a2 = m2;
}
__device__ __forceinline__ unsigned packkey(float f, unsigned idx) {
    unsigned u = __float_as_uint(f);
    unsigned tt = (unsigned)((int)u >> 31) | 0x80000000u;
    return ((u ^ tt) & 0xFFFFE000u) | (8191u - idx);
}

// ------- Kernel 3: symmetric bf16 MFMA sim, 128x128 tiles, triangular 1-D grid -------
// Linear block L -> (ib <= jbk). Direct epilogue -> pkeys[row][jbk]; strictly-upper
// blocks also emit per-col top-3 -> pkeys[col][ib]. Exact slot cover, no memset.
__global__ __launch_bounds__(256)
void sim_mfma_kernel(const short* __restrict__ projb, unsigned* __restrict__ pkeys) {
    const int L = blockIdx.x;
    int jbk = (int)((sqrtf(8.0f * L + 1.0f) - 1.0f) * 0.5f);
    while ((jbk + 1) * (jbk + 2) / 2 <= L) ++jbk;
    while (jbk * (jbk + 1) / 2 > L) --jbk;
    const int ib = L - jbk * (jbk + 1) / 2;    // 0..jbk
    const bool do_tr = (ib < jbk);

    __shared__ short smem[2 * TB * BK * 2];   // 32 KB: As[2][128*32], Bs[2][128*32]
    short* As = smem;
    short* Bs = smem + 2 * TB * BK;
    unsigned* evu = (unsigned*)smem;          // direct overlay [128][25]
    unsigned* evt = (unsigned*)smem + 3200;   // transposed overlay [128][6]

    const int t = threadIdx.x;
    const int w = t >> 6, l = t & 63;
    const int wr = w >> 1, wc = w & 1;
    const int tx = l & 15, tg = l >> 4;
    const int rb = ib * TB;
    const int jb = jbk * TB;

    const int rin = l >> 2;
    const int tgs = (l & 3) ^ ((rin >> 1) & 3);
    const int loff = tx * BK + ((tg ^ ((tx >> 1) & 3)) << 3);

    f32x4 acc[4][4];
#pragma unroll
    for (int i = 0; i < 4; ++i)
#pragma unroll
        for (int j = 0; j < 4; ++j) acc[i][j] = (f32x4){0.f, 0.f, 0.f, 0.f};

#define STAGE(buf, k0)                                                                      \
    {                                                                                       \
        _Pragma("unroll")                                                                   \
        for (int q = 0; q < 2; ++q) {                                                       \
            int c = w * 2 + q;                                                              \
            const short* ga = projb + (size_t)(rb + c * 16 + rin) * DD + (k0) + tgs * 8;    \
            __builtin_amdgcn_global_load_lds(AS1(ga), AS3(As + (buf) * (TB * BK) + c * 512 + l * 8), 16, 0, 0); \
            const short* gb = projb + (size_t)(jb + c * 16 + rin) * DD + (k0) + tgs * 8;    \
            __builtin_amdgcn_global_load_lds(AS1(gb), AS3(Bs + (buf) * (TB * BK) + c * 512 + l * 8), 16, 0, 0); \
        }                                                                                   \
    }

#define COMPUTE(kt)                                                                          \
    {                                                                                        \
        const short* Ab = As + ((kt) & 1) * (TB * BK);                                       \
        const short* Bb = Bs + ((kt) & 1) * (TB * BK);                                       \
        bf16x8 af[4], bfr[4];                                                                \
        _Pragma("unroll")                                                                    \
        for (int mi = 0; mi < 4; ++mi)                                                       \
            af[mi] = *(const bf16x8*)&Ab[(wr * 64 + mi * 16) * BK + loff];                   \
        _Pragma("unroll")                                                                    \
        for (int nj = 0; nj < 4; ++nj)                                                       \
            bfr[nj] = *(const bf16x8*)&Bb[(wc * 64 + nj * 16) * BK + loff];                  \
        asm volatile("s_waitcnt lgkmcnt(0)" ::: "memory");                                   \
        __builtin_amdgcn_sched_barrier(0);                                                   \
        __builtin_amdgcn_s_barrier();                                                        \
        __builtin_amdgcn_sched_barrier(0);                                                   \
        _Pragma("unroll")                                                                    \
        for (int mi = 0; mi < 4; ++mi)                                                       \
            _Pragma("unroll")                                                                \
            for (int nj = 0; nj < 4; ++nj)                                                   \
                acc[mi][nj] = __builtin_amdgcn_mfma_f32_16x16x32_bf16(af[mi], bfr[nj], acc[mi][nj], 0, 0, 0); \
    }

    STAGE(0, 0);
    for (int kt = 0; kt < KT - 1; ++kt) {
        STAGE((kt + 1) & 1, (kt + 1) * BK);
        asm volatile("s_waitcnt vmcnt(4)" ::: "memory");
        __builtin_amdgcn_sched_barrier(0);
        __builtin_amdgcn_s_barrier();
        __builtin_amdgcn_sched_barrier(0);
        COMPUTE(kt);
    }
    asm volatile("s_waitcnt vmcnt(0)" ::: "memory");
    __builtin_amdgcn_sched_barrier(0);
    __builtin_amdgcn_s_barrier();
    __builtin_amdgcn_sched_barrier(0);
    COMPUTE(KT - 1);
#undef STAGE
#undef COMPUTE

    __syncthreads();   // K-loop done everywhere before LDS overlay

    // ---- direct epilogue: per-row top3 over this block's 128 cols ----
    unsigned cinv[4];
#pragma unroll
    for (int nj = 0; nj < 4; ++nj)
        cinv[nj] = 8191u - (unsigned)(jb + wc * 64 + nj * 16 + tx);
#pragma unroll
    for (int mi = 0; mi < 4; ++mi) {
#pragma unroll
        for (int rr = 0; rr < 4; ++rr) {
            unsigned k0 = 0, k1 = 0, k2 = 0;
#pragma unroll
            for (int nj = 0; nj < 4; ++nj) {
                unsigned u = __float_as_uint(acc[mi][nj][rr]);
                unsigned tt = (unsigned)((int)u >> 31) | 0x80000000u;
                ins3k(((u ^ tt) & 0xFFFFE000u) | cinv[nj], k0, k1, k2);
            }
#pragma unroll
            for (int s = 1; s <= 2; s <<= 1) {
                unsigned b0 = (unsigned)__shfl_xor((int)k0, s, 64);
                unsigned b1 = (unsigned)__shfl_xor((int)k1, s, 64);
                unsigned b2 = (unsigned)__shfl_xor((int)k2, s, 64);
                merge3k(k0, k1, k2, b0, b1, b2);
            }
            if ((tx & 3) == 0) {
                int lrow = wr * 64 + mi * 16 + tg * 4 + rr;
                unsigned* e = &evu[lrow * 25 + (wc * 4 + (tx >> 2)) * 3];
                e[0] = k0; e[1] = k1; e[2] = k2;
            }
        }
    }

    // ---- transposed epilogue (strictly-upper): per-col top3 over this block's 128 rows ----
    if (do_tr) {
#pragma unroll
        for (int nj = 0; nj < 4; ++nj) {
            unsigned k0 = 0, k1 = 0, k2 = 0;
#pragma unroll
            for (int mi = 0; mi < 4; ++mi) {
#pragma unroll
                for (int rr = 0; rr < 4; ++rr) {
                    unsigned idx = (unsigned)(rb + wr * 64 + mi * 16 + tg * 4 + rr);
                    ins3k(packkey(acc[mi][nj][rr], idx), k0, k1, k2);
                }
            }
#pragma unroll
            for (int s = 16; s <= 32; s <<= 1) {
                unsigned b0 = (unsigned)__shfl_xor((int)k0, s, 64);
                unsigned b1 = (unsigned)__shfl_xor((int)k1, s, 64);
                unsigned b2 = (unsigned)__shfl_xor((int)k2, s, 64);
                merge3k(k0, k1, k2, b0, b1, b2);
            }
            if (tg == 0) {
                int col = wc * 64 + nj * 16 + tx;
                unsigned* e = &evt[col * 6 + wr * 3];
                e[0] = k0; e[1] = k1; e[2] = k2;
            }
        }
    }
    __syncthreads();

    if (t < TB) {
        unsigned k0 = 0, k1 = 0, k2 = 0;
        const unsigned* e = &evu[t * 25];
#pragma unroll
        for (int s = 0; s < 24; ++s) ins3k(e[s], k0, k1, k2);
        unsigned* pk = pkeys + (size_t)(rb + t) * ROWKEYS + jbk * 3;
        pk[0] = k0; pk[1] = k1; pk[2] = k2;
    }
    if (do_tr && t < TB) {
        unsigned k0 = 0, k1 = 0, k2 = 0;
        const unsigned* e = &evt[t * 6];
#pragma unroll
        for (int s = 0; s < 6; ++s) ins3k(e[s], k0, k1, k2);
        unsigned* pk = pkeys + (size_t)(jb + t) * ROWKEYS + ib * 3;
        pk[0] = k0; pk[1] = k1; pk[2] = k2;
    }
}

// --- Kernel 4: parallel top-8 of 192 keys + exact fp64 re-rank + softmax + gather + out ---
// 4 rows per block (4 independent waves). Lane t holds keys [3t..3t+2] (coalesced load);
// top-8 extracted by 8x wave-max (keys unique: index embedded) -> same set as serial scan.
__global__ __launch_bounds__(256)
void rerank_out_kernel(const float* __restrict__ proj, const unsigned* __restrict__ pkeys,
                       const float* __restrict__ sess, float* __restrict__ out,
                       float* __restrict__ cos_out) {
    int r = blockIdx.x * 4 + (threadIdx.x >> 6);
    int t = threadIdx.x & 63;
    const unsigned* pk = pkeys + (size_t)r * ROWKEYS;
    unsigned a0 = pk[3 * t], a1 = pk[3 * t + 1], a2 = pk[3 * t + 2];
    // sort descending (slot triples are already sorted, but make no assumption)
    {
        unsigned m01 = a0 > a1 ? a0 : a1, n01 = a0 > a1 ? a1 : a0;
        unsigned m2 = n01 > a2 ? n01 : a2, n2 = n01 > a2 ? a2 : n01;
        a0 = m01 > m2 ? m01 : m2;
        a1 = m01 > m2 ? m2 : m01;   // note: m01>=n01, m2>=n2; second largest = min(m01, m2)
        a2 = n2;
    }
    unsigned ck[NCAND];
#pragma unroll
    for (int i = 0; i < NCAND; ++i) {
        unsigned m = a0;
#pragma unroll
        for (int s = 1; s < 64; s <<= 1) {
            unsigned o = (unsigned)__shfl_xor((int)m, s, 64);
            m = m > o ? m : o;
        }
        ck[i] = m;
        if (a0 == m) { a0 = a1; a1 = a2; a2 = 0; }   // unique keys -> exactly one lane pops
    }
    int cj[NCAND];
#pragma unroll
    for (int i = 0; i < NCAND; ++i) cj[i] = 8191 - (int)(ck[i] & 0x1FFFu);

    const float* pr = proj + (size_t)r * DD;
    float myp[8];
#pragma unroll
    for (int k = 0; k < 8; ++k) myp[k] = pr[t * 8 + k];
    double part[NCAND];
#pragma unroll
    for (int i = 0; i < NCAND; ++i) {
        const float* pc = proj + (size_t)cj[i] * DD;
        double s = 0.0;
#pragma unroll
        for (int k = 0; k < 8; ++k) s += (double)myp[k] * (double)pc[t * 8 + k];
        part[i] = s;
    }
#pragma unroll
    for (int i = 0; i < NCAND; ++i) {
#pragma unroll
        for (int s = 1; s < 64; s <<= 1) part[i] += __shfl_xor(part[i], s, 64);
    }
    double bv0 = -1e300, bv1 = -1e300, bv2 = -1e300;
    int bj0 = 0x7fffffff, bj1 = 0x7fffffff, bj2 = 0x7fffffff;
#pragma unroll
    for (int i = 0; i < NCAND; ++i) {
        double v = part[i]; int j = cj[i];
        bool g2 = (v > bv2) || (v == bv2 && j < bj2);
        bool g1 = (v > bv1) || (v == bv1 && j < bj1);
        bool g0 = (v > bv0) || (v == bv0 && j < bj0);
        if (g2) {
            if (g1) {
                if (g0) { bv2 = bv1; bj2 = bj1; bv1 = bv0; bj1 = bj0; bv0 = v; bj0 = j; }
                else    { bv2 = bv1; bj2 = bj1; bv1 = v; bj1 = j; }
            } else      { bv2 = v; bj2 = j; }
        }
    }
    double e1 = exp(bv1 - bv0), e2 = exp(bv2 - bv0);
    double inv = 1.0 / (1.0 + e1 + e2);
    float w0 = (float)inv, w1 = (float)(e1 * inv), w2 = (float)(e2 * inv);
    if (t == 0) {
        cos_out[r * 3 + 0] = w0; cos_out[r * 3 + 1] = w1; cos_out[r * 3 + 2] = w2;
    }
    const float4* s0 = (const float4*)(sess + (size_t)bj0 * DD);
    const float4* s1 = (const float4*)(sess + (size_t)bj1 * DD);
    const float4* s2 = (const float4*)(sess + (size_t)bj2 * DD);
    float4* o = (float4*)(out + (size_t)r * 3 * DD);
    float4* nb = (float4*)(out + (size_t)NB * 3 * DD + (size_t)r * DD);
#pragma unroll
    for (int e = 0; e < 2; ++e) {
        int q = t + e * 64;
        float4 x0 = s0[q], x1 = s1[q], x2 = s2[q];
        o[q] = x0; o[128 + q] = x1; o[256 + q] = x2;
        float4 v;
        v.x = fmaf(w0, x0.x, fmaf(w1, x1.x, w2 * x2.x));
        v.y = fmaf(w0, x0.y, fmaf(w1, x1.y, w2 * x2.y));
        v.z = fmaf(w0, x0.z, fmaf(w1, x1.z, w2 * x2.z));
        v.w = fmaf(w0, x0.w, fmaf(w1, x1.w, w2 * x2.w));
        nb[q] = v;
    }
}

extern "C" void kernel_launch(void* const* d_in, const int* in_sizes, int n_in,
                              void* d_out, int out_size, void* d_ws, size_t ws_size,
                              hipStream_t stream) {
    const float* sess = (const float*)d_in[0];
    // d_in[1] = pool_emb: unused by the reference
    const float* W1 = (const float*)d_in[2];
    const float* b1 = (const float*)d_in[3];
    const float* W2 = (const float*)d_in[4];
    const float* b2 = (const float*)d_in[5];
    float* out = (float*)d_out;

    const size_t MBc = 1u << 20;
    char* W = (char*)d_ws;
    // [0,16MB): sess_hi+sess_lo during prep/gemm1; proj f32 afterwards (stream-serialized)
    float*   proj    = (float*)W;
    ushortT* sess_hi = (ushortT*)W;
    ushortT* sess_lo = sess_hi + (size_t)NB * DD;
    ushortT* projb   = (ushortT*)(W + 16 * MBc);          // 8 MB
    ushortT* h_hi    = (ushortT*)(W + 24 * MBc);          // 4 MB (dead after gemm2)
    ushortT* h_lo    = (ushortT*)(W + 28 * MBc);          // 4 MB (dead after gemm2)
    ushortT* w1t_hi  = (ushortT*)(W + 32 * MBc);
    ushortT* w1t_lo  = w1t_hi + 256 * 512;
    ushortT* w2t_hi  = w1t_lo + 256 * 512;
    ushortT* w2t_lo  = w2t_hi + 512 * 256;
    unsigned* pkeys  = (unsigned*)(W + 24 * MBc);         // overlays h_hi/h_lo: 6.3 MB

    float* cos_out = out + (size_t)NB * 3 * DD + (size_t)NB * DD;

    hipLaunchKernelGGL(prep_kernel, dim3(2176), dim3(256), 0, stream,
                       sess, W1, W2, sess_hi, sess_lo, w1t_hi, w1t_lo, w2t_hi, w2t_lo);
    hipLaunchKernelGGL((mlp_gemm<512, 256, 0>), dim3(NB / 64, 1), dim3(256), 0, stream,
                       sess_hi, sess_lo, w1t_hi, w1t_lo, b1, h_hi, h_lo, (float*)nullptr, (ushortT*)nullptr);
    hipLaunchKernelGGL((mlp_gemm<256, 512, 1>), dim3(NB / 64, 2), dim3(256), 0, stream,
                       h_hi, h_lo, w2t_hi, w2t_lo, b2, (ushortT*)nullptr, (ushortT*)nullptr, proj, projb);
    hipLaunchKernelGGL(sim_mfma_kernel, dim3(NTRI), dim3(256), 0, stream,
                       (const short*)projb, pkeys);
    hipLaunchKernelGGL(rerank_out_kernel, dim3(NB / 4), dim3(256), 0, stream,
                       proj, pkeys, sess, out, cos_out);
}

// Round 11
// 141.943 us; speedup vs baseline: 1.6566x; 1.0540x over previous
//
#include <hip/hip_runtime.h>
#include <hip/hip_bf16.h>
#include <math.h>

#define NB 8192
#define DD 512
#define HH 256
#define TB 128             // sim tile 128x128
#define BK 32              // mlp gemm k-tile
#define BK2 64             // sim k-tile
#define KT2 (DD / BK2)     // 8 k-steps in sim
#define NSLOT 64
#define ROWKEYS (NSLOT * 3)
#define NCAND 8
#define NTRI 2080          // 64*65/2

typedef unsigned short ushortT;
typedef __attribute__((ext_vector_type(8))) short bf16x8;
typedef __attribute__((ext_vector_type(4))) float f32x4;

#define AS1(p) ((const __attribute__((address_space(1))) void*)(p))
#define AS3(p) ((__attribute__((address_space(3))) void*)(p))

__device__ __forceinline__ ushortT bf16rne(float f) {
    unsigned u = __float_as_uint(f);
    unsigned r = u + 0x7FFFu + ((u >> 16) & 1u);
    return (ushortT)(r >> 16);
}
__device__ __forceinline__ float bf16tof(ushortT h) {
    return __uint_as_float(((unsigned)h) << 16);
}

// ---------------- Kernel 0: prep ----------------
__global__ __launch_bounds__(256)
void prep_kernel(const float* __restrict__ sess, const float* __restrict__ W1,
                 const float* __restrict__ W2,
                 ushortT* __restrict__ sess_hi, ushortT* __restrict__ sess_lo,
                 ushortT* __restrict__ w1t_hi, ushortT* __restrict__ w1t_lo,
                 ushortT* __restrict__ w2t_hi, ushortT* __restrict__ w2t_lo) {
    const int b = blockIdx.x, t = threadIdx.x;
    if (b < 2048) {
        size_t i = (size_t)b * 2048 + t * 8;
        float4 f0 = *(const float4*)&sess[i];
        float4 f1 = *(const float4*)&sess[i + 4];
        float f[8] = {f0.x, f0.y, f0.z, f0.w, f1.x, f1.y, f1.z, f1.w};
        unsigned hp[4], lp[4];
#pragma unroll
        for (int j = 0; j < 4; ++j) {
            ushortT h0 = bf16rne(f[2 * j]), h1 = bf16rne(f[2 * j + 1]);
            ushortT l0 = bf16rne(f[2 * j] - bf16tof(h0));
            ushortT l1 = bf16rne(f[2 * j + 1] - bf16tof(h1));
            hp[j] = (unsigned)h0 | ((unsigned)h1 << 16);
            lp[j] = (unsigned)l0 | ((unsigned)l1 << 16);
        }
        *(uint4*)&sess_hi[i] = *(uint4*)hp;
        *(uint4*)&sess_lo[i] = *(uint4*)lp;
    } else if (b < 2112) {
        int o = (b - 2048) * 2048 + t * 8;
        int k = o >> 8, c = o & 255;
        float4 f0 = *(const float4*)&W1[(size_t)k * 256 + c];
        float4 f1 = *(const float4*)&W1[(size_t)k * 256 + c + 4];
        float f[8] = {f0.x, f0.y, f0.z, f0.w, f1.x, f1.y, f1.z, f1.w};
#pragma unroll
        for (int j = 0; j < 8; ++j) {
            ushortT h = bf16rne(f[j]);
            w1t_hi[(size_t)(c + j) * 512 + k] = h;
            w1t_lo[(size_t)(c + j) * 512 + k] = bf16rne(f[j] - bf16tof(h));
        }
    } else {
        int o = (b - 2112) * 2048 + t * 8;
        int k = o >> 9, c = o & 511;
        float4 f0 = *(const float4*)&W2[(size_t)k * 512 + c];
        float4 f1 = *(const float4*)&W2[(size_t)k * 512 + c + 4];
        float f[8] = {f0.x, f0.y, f0.z, f0.w, f1.x, f1.y, f1.z, f1.w};
#pragma unroll
        for (int j = 0; j < 8; ++j) {
            ushortT h = bf16rne(f[j]);
            w2t_hi[(size_t)(c + j) * 256 + k] = h;
            w2t_lo[(size_t)(c + j) * 256 + k] = bf16rne(f[j] - bf16tof(h));
        }
    }
}

// -------- Kernel 1/2: split-bf16 MFMA GEMM, C = A @ B^T (+bias), TM x 256 tile --------
template <int KDIM, int NOUT, int EPI, int TM>
__global__ __launch_bounds__(256)
void mlp_gemm(const ushortT* __restrict__ Ahi, const ushortT* __restrict__ Alo,
              const ushortT* __restrict__ Bhi, const ushortT* __restrict__ Blo,
              const float* __restrict__ bias,
              ushortT* __restrict__ Ohi, ushortT* __restrict__ Olo,
              float* __restrict__ Of, ushortT* __restrict__ Ob) {
    constexpr int AC = TM / 16;           // 16-row chunks per A matrix
    constexpr int CHUNKS = 2 * AC + 32;   // total 1KB chunks per K-step
    constexpr int QN = CHUNKS / 4;        // chunks per wave
    constexpr int BUFS = CHUNKS * 512;    // shorts per buffer
    constexpr int MI = TM / 32;           // m-frags per wave
    __shared__ short gsmem[2 * BUFS];
    const int KTILES = KDIM / BK;
    const int t = threadIdx.x;
    const int w = t >> 6, l = t & 63;
    const int wr = w >> 1, wc = w & 1;
    const int tx = l & 15, tg = l >> 4;
    const int rb = blockIdx.x * TM;
    const int cb = blockIdx.y * 256;

    const int rin = l >> 2;
    const int tgs = (l & 3) ^ ((rin >> 1) & 3);
    const int loff = tx * BK + ((tg ^ ((tx >> 1) & 3)) << 3);

    f32x4 acc[MI][8];
#pragma unroll
    for (int i = 0; i < MI; ++i)
#pragma unroll
        for (int j = 0; j < 8; ++j) acc[i][j] = (f32x4){0.f, 0.f, 0.f, 0.f};

#define GSTAGE(buf, k0v)                                                                     \
    {                                                                                        \
        _Pragma("unroll")                                                                    \
        for (int q = 0; q < QN; ++q) {                                                       \
            int c = w * QN + q;                                                              \
            const ushortT* src; int row; int lofs;                                           \
            if (c < AC)            { src = Ahi; row = rb + c * 16 + rin;             lofs = c * 512; }                  \
            else if (c < 2 * AC)   { src = Alo; row = rb + (c - AC) * 16 + rin;      lofs = c * 512; }                  \
            else if (c < 2*AC+16)  { src = Bhi; row = cb + (c - 2*AC) * 16 + rin;    lofs = c * 512; }                  \
            else                   { src = Blo; row = cb + (c - 2*AC - 16) * 16 + rin; lofs = c * 512; }                \
            const ushortT* g = src + (size_t)row * KDIM + (k0v) + tgs * 8;                   \
            __builtin_amdgcn_global_load_lds(AS1(g), AS3(gsmem + (buf) * BUFS + lofs + l * 8), 16, 0, 0); \
        }                                                                                    \
    }

#define GCOMPUTE(kt)                                                                         \
    {                                                                                        \
        const short* Bu = gsmem + ((kt) & 1) * BUFS;                                         \
        bf16x8 ah[MI], al[MI], bh[8], bl[8];                                                 \
        _Pragma("unroll")                                                                    \
        for (int mi = 0; mi < MI; ++mi) {                                                    \
            ah[mi] = *(const bf16x8*)&Bu[(wr * MI + mi) * 512 + loff];                       \
            al[mi] = *(const bf16x8*)&Bu[AC * 512 + (wr * MI + mi) * 512 + loff];            \
        }                                                                                    \
        _Pragma("unroll")                                                                    \
        for (int nj = 0; nj < 8; ++nj) {                                                     \
            bh[nj] = *(const bf16x8*)&Bu[2 * AC * 512 + (wc * 8 + nj) * 512 + loff];         \
            bl[nj] = *(const bf16x8*)&Bu[(2 * AC + 16) * 512 + (wc * 8 + nj) * 512 + loff];  \
        }                                                                                    \
        asm volatile("s_waitcnt lgkmcnt(0)" ::: "memory");                                   \
        __builtin_amdgcn_sched_barrier(0);                                                   \
        __builtin_amdgcn_s_barrier();                                                        \
        __builtin_amdgcn_sched_barrier(0);                                                   \
        _Pragma("unroll")                                                                    \
        for (int mi = 0; mi < MI; ++mi)                                                      \
            _Pragma("unroll")                                                                \
            for (int nj = 0; nj < 8; ++nj) {                                                 \
                acc[mi][nj] = __builtin_amdgcn_mfma_f32_16x16x32_bf16(ah[mi], bh[nj], acc[mi][nj], 0, 0, 0); \
                acc[mi][nj] = __builtin_amdgcn_mfma_f32_16x16x32_bf16(ah[mi], bl[nj], acc[mi][nj], 0, 0, 0); \
                acc[mi][nj] = __builtin_amdgcn_mfma_f32_16x16x32_bf16(al[mi], bh[nj], acc[mi][nj], 0, 0, 0); \
            }                                                                                \
    }

    GSTAGE(0, 0);
    for (int kt = 0; kt < KTILES - 1; ++kt) {
        GSTAGE((kt + 1) & 1, (kt + 1) * BK);
        if constexpr (TM == 64) { asm volatile("s_waitcnt vmcnt(10)" ::: "memory"); }
        else                    { asm volatile("s_waitcnt vmcnt(9)" ::: "memory"); }
        __builtin_amdgcn_sched_barrier(0);
        __builtin_amdgcn_s_barrier();
        __builtin_amdgcn_sched_barrier(0);
        GCOMPUTE(kt);
    }
    asm volatile("s_waitcnt vmcnt(0)" ::: "memory");
    __builtin_amdgcn_sched_barrier(0);
    __builtin_amdgcn_s_barrier();
    __builtin_amdgcn_sched_barrier(0);
    GCOMPUTE(KTILES - 1);
#undef GSTAGE
#undef GCOMPUTE

#pragma unroll
    for (int mi = 0; mi < MI; ++mi) {
#pragma unroll
        for (int nj = 0; nj < 8; ++nj) {
            int col = cb + wc * 128 + nj * 16 + tx;
            float bv = bias[col];
#pragma unroll
            for (int rr = 0; rr < 4; ++rr) {
                int row = rb + wr * (TM / 2) + mi * 16 + tg * 4 + rr;
                float v = acc[mi][nj][rr] + bv;
                if (EPI == 0) {
                    v = fmaxf(v, 0.f);
                    ushortT h = bf16rne(v);
                    Ohi[(size_t)row * NOUT + col] = h;
                    Olo[(size_t)row * NOUT + col] = bf16rne(v - bf16tof(h));
                } else {
                    Of[(size_t)row * NOUT + col] = v;
                    Ob[(size_t)row * NOUT + col] = bf16rne(v);
                }
            }
        }
    }
}

// ---- packed-key top-3 helpers ----
__device__ __forceinline__ void ins3k(unsigned key, unsigned& k0, unsigned& k1, unsigned& k2) {
    bool g0 = key > k0, g1 = key > k1, g2 = key > k2;
    k2 = g1 ? k1 : (g2 ? key : k2);
    k1 = g0 ? k0 : (g1 ? key : k1);
    k0 = g0 ? key : k0;
}
__device__ __forceinline__ void merge3k(unsigned& a0, unsigned& a1, unsigned& a2,
                                        unsigned b0, unsigned b1, unsigned b2) {
    unsigned m0 = a0 > b0 ? a0 : b0;
    bool c0 = a0 > b0;
    unsigned ca1 = c0 ? a1 : b1;
    unsigned cb0 = c0 ? b0 : a0;
    unsigned ca2 = c0 ? a2 : b2;
    unsigned cb1 = c0 ? b1 : a1;
    bool c1 = ca1 > cb0;
    unsigned m1 = c1 ? ca1 : cb0;
    unsigned x = c1 ? ca2 : ca1;
    unsigned y = c1 ? cb0 : cb1;
    unsigned m2 = x > y ? x : y;
    a0 = m0; a1 = m1; a2 = m2;
}
__device__ __forceinline__ unsigned packkey(float f, unsigned idx) {
    unsigned u = __float_as_uint(f);
    unsigned tt = (unsigned)((int)u >> 31) | 0x80000000u;
    return ((u ^ tt) & 0xFFFFE000u) | (8191u - idx);
}

// ------- Kernel 3: symmetric bf16 MFMA sim, 128x128 tiles, BK=64, XCD-chunked triangle -------
__global__ __launch_bounds__(256)
void sim_mfma_kernel(const short* __restrict__ projb, unsigned* __restrict__ pkeys) {
    // XCD-chunked bijective remap: 2080 = 8*260; XCD k gets 260 consecutive L (panel reuse in L2)
    const int b = blockIdx.x;
    const int L = (b & 7) * 260 + (b >> 3);
    int jbk = (int)((sqrtf(8.0f * L + 1.0f) - 1.0f) * 0.5f);
    while ((jbk + 1) * (jbk + 2) / 2 <= L) ++jbk;
    while (jbk * (jbk + 1) / 2 > L) --jbk;
    const int ib = L - jbk * (jbk + 1) / 2;
    const bool do_tr = (ib < jbk);

    __shared__ short smem[2 * TB * BK2 * 2];   // 64 KB: As[2][128*64], Bs[2][128*64]
    short* As = smem;
    short* Bs = smem + 2 * TB * BK2;
    unsigned* evu = (unsigned*)smem;           // epilogue overlay [128][25]
    unsigned* evt = (unsigned*)smem + 3200;    // transposed overlay [128][6]

    const int t = threadIdx.x;
    const int w = t >> 6, l = t & 63;
    const int wr = w >> 1, wc = w & 1;
    const int tx = l & 15, tg = l >> 4;
    const int rb = ib * TB;
    const int jb = jbk * TB;

    // staging: chunk = 8 rows x 128B; lane l -> row l>>3, phys slot l&7; fetch slot = phys ^ row%8
    const int sl8 = (((l & 7) ^ (l >> 3)) << 3);
    // read swizzle: phys slot = (ks*4+tg) ^ (row&7), row&7 == tx&7
    const int sw0 = (((0 + tg) ^ (tx & 7)) << 3);
    const int sw1 = (((4 + tg) ^ (tx & 7)) << 3);

    f32x4 acc[4][4];
#pragma unroll
    for (int i = 0; i < 4; ++i)
#pragma unroll
        for (int j = 0; j < 4; ++j) acc[i][j] = (f32x4){0.f, 0.f, 0.f, 0.f};

#define STAGE(buf, k0)                                                                      \
    {                                                                                       \
        _Pragma("unroll")                                                                   \
        for (int q = 0; q < 4; ++q) {                                                       \
            int c = w * 4 + q;                                                              \
            const short* ga = projb + (size_t)(rb + c * 8 + (l >> 3)) * DD + (k0) + sl8;    \
            __builtin_amdgcn_global_load_lds(AS1(ga), AS3(As + (buf) * 8192 + c * 512 + l * 8), 16, 0, 0); \
            const short* gb = projb + (size_t)(jb + c * 8 + (l >> 3)) * DD + (k0) + sl8;    \
            __builtin_amdgcn_global_load_lds(AS1(gb), AS3(Bs + (buf) * 8192 + c * 512 + l * 8), 16, 0, 0); \
        }                                                                                   \
    }

#define COMPUTE(kt)                                                                          \
    {                                                                                        \
        const short* Ab = As + ((kt) & 1) * 8192;                                            \
        const short* Bb = Bs + ((kt) & 1) * 8192;                                            \
        bf16x8 af0[4], af1[4], bf0[4], bf1[4];                                               \
        _Pragma("unroll")                                                                    \
        for (int mi = 0; mi < 4; ++mi) {                                                     \
            int row = wr * 64 + mi * 16 + tx;                                                \
            af0[mi] = *(const bf16x8*)&Ab[row * 64 + sw0];                                   \
            af1[mi] = *(const bf16x8*)&Ab[row * 64 + sw1];                                   \
        }                                                                                    \
        _Pragma("unroll")                                                                    \
        for (int nj = 0; nj < 4; ++nj) {                                                     \
            int row = wc * 64 + nj * 16 + tx;                                                \
            bf0[nj] = *(const bf16x8*)&Bb[row * 64 + sw0];                                   \
            bf1[nj] = *(const bf16x8*)&Bb[row * 64 + sw1];                                   \
        }                                                                                    \
        asm volatile("s_waitcnt lgkmcnt(0)" ::: "memory");                                   \
        __builtin_amdgcn_sched_barrier(0);                                                   \
        __builtin_amdgcn_s_barrier();                                                        \
        __builtin_amdgcn_sched_barrier(0);                                                   \
        _Pragma("unroll")                                                                    \
        for (int mi = 0; mi < 4; ++mi)                                                       \
            _Pragma("unroll")                                                                \
            for (int nj = 0; nj < 4; ++nj)                                                   \
                acc[mi][nj] = __builtin_amdgcn_mfma_f32_16x16x32_bf16(af0[mi], bf0[nj], acc[mi][nj], 0, 0, 0); \
        _Pragma("unroll")                                                                    \
        for (int mi = 0; mi < 4; ++mi)                                                       \
            _Pragma("unroll")                                                                \
            for (int nj = 0; nj < 4; ++nj)                                                   \
                acc[mi][nj] = __builtin_amdgcn_mfma_f32_16x16x32_bf16(af1[mi], bf1[nj], acc[mi][nj], 0, 0, 0); \
    }

    STAGE(0, 0);
    for (int kt = 0; kt < KT2 - 1; ++kt) {
        STAGE((kt + 1) & 1, (kt + 1) * BK2);
        asm volatile("s_waitcnt vmcnt(8)" ::: "memory");
        __builtin_amdgcn_sched_barrier(0);
        __builtin_amdgcn_s_barrier();
        __builtin_amdgcn_sched_barrier(0);
        COMPUTE(kt);
    }
    asm volatile("s_waitcnt vmcnt(0)" ::: "memory");
    __builtin_amdgcn_sched_barrier(0);
    __builtin_amdgcn_s_barrier();
    __builtin_amdgcn_sched_barrier(0);
    COMPUTE(KT2 - 1);
#undef STAGE
#undef COMPUTE

    __syncthreads();   // K-loop done everywhere before LDS overlay

    // ---- direct epilogue: per-row top3 over this block's 128 cols ----
    unsigned cinv[4];
#pragma unroll
    for (int nj = 0; nj < 4; ++nj)
        cinv[nj] = 8191u - (unsigned)(jb + wc * 64 + nj * 16 + tx);
#pragma unroll
    for (int mi = 0; mi < 4; ++mi) {
#pragma unroll
        for (int rr = 0; rr < 4; ++rr) {
            unsigned k0 = 0, k1 = 0, k2 = 0;
#pragma unroll
            for (int nj = 0; nj < 4; ++nj) {
                unsigned u = __float_as_uint(acc[mi][nj][rr]);
                unsigned tt = (unsigned)((int)u >> 31) | 0x80000000u;
                ins3k(((u ^ tt) & 0xFFFFE000u) | cinv[nj], k0, k1, k2);
            }
#pragma unroll
            for (int s = 1; s <= 2; s <<= 1) {
                unsigned b0 = (unsigned)__shfl_xor((int)k0, s, 64);
                unsigned b1 = (unsigned)__shfl_xor((int)k1, s, 64);
                unsigned b2 = (unsigned)__shfl_xor((int)k2, s, 64);
                merge3k(k0, k1, k2, b0, b1, b2);
            }
            if ((tx & 3) == 0) {
                int lrow = wr * 64 + mi * 16 + tg * 4 + rr;
                unsigned* e = &evu[lrow * 25 + (wc * 4 + (tx >> 2)) * 3];
                e[0] = k0; e[1] = k1; e[2] = k2;
            }
        }
    }

    // ---- transposed epilogue (strictly-upper): per-col top3 over this block's 128 rows ----
    if (do_tr) {
#pragma unroll
        for (int nj = 0; nj < 4; ++nj) {
            unsigned k0 = 0, k1 = 0, k2 = 0;
#pragma unroll
            for (int mi = 0; mi < 4; ++mi) {
#pragma unroll
                for (int rr = 0; rr < 4; ++rr) {
                    unsigned idx = (unsigned)(rb + wr * 64 + mi * 16 + tg * 4 + rr);
                    ins3k(packkey(acc[mi][nj][rr], idx), k0, k1, k2);
                }
            }
#pragma unroll
            for (int s = 16; s <= 32; s <<= 1) {
                unsigned b0 = (unsigned)__shfl_xor((int)k0, s, 64);
                unsigned b1 = (unsigned)__shfl_xor((int)k1, s, 64);
                unsigned b2 = (unsigned)__shfl_xor((int)k2, s, 64);
                merge3k(k0, k1, k2, b0, b1, b2);
            }
            if (tg == 0) {
                int col = wc * 64 + nj * 16 + tx;
                unsigned* e = &evt[col * 6 + wr * 3];
                e[0] = k0; e[1] = k1; e[2] = k2;
            }
        }
    }
    __syncthreads();

    if (t < TB) {
        unsigned k0 = 0, k1 = 0, k2 = 0;
        const unsigned* e = &evu[t * 25];
#pragma unroll
        for (int s = 0; s < 24; ++s) ins3k(e[s], k0, k1, k2);
        unsigned* pk = pkeys + (size_t)(rb + t) * ROWKEYS + jbk * 3;
        pk[0] = k0; pk[1] = k1; pk[2] = k2;
    }
    if (do_tr && t < TB) {
        unsigned k0 = 0, k1 = 0, k2 = 0;
        const unsigned* e = &evt[t * 6];
#pragma unroll
        for (int s = 0; s < 6; ++s) ins3k(e[s], k0, k1, k2);
        unsigned* pk = pkeys + (size_t)(jb + t) * ROWKEYS + ib * 3;
        pk[0] = k0; pk[1] = k1; pk[2] = k2;
    }
}

// --- Kernel 4: parallel top-8 of 192 keys + exact fp64 re-rank + softmax + gather + out ---
__global__ __launch_bounds__(256)
void rerank_out_kernel(const float* __restrict__ proj, const unsigned* __restrict__ pkeys,
                       const float* __restrict__ sess, float* __restrict__ out,
                       float* __restrict__ cos_out) {
    int r = blockIdx.x * 4 + (threadIdx.x >> 6);
    int t = threadIdx.x & 63;
    const unsigned* pk = pkeys + (size_t)r * ROWKEYS;
    unsigned a0 = pk[3 * t], a1 = pk[3 * t + 1], a2 = pk[3 * t + 2];
    {
        unsigned m01 = a0 > a1 ? a0 : a1, n01 = a0 > a1 ? a1 : a0;
        unsigned m2 = n01 > a2 ? n01 : a2, n2 = n01 > a2 ? a2 : n01;
        a0 = m01 > m2 ? m01 : m2;
        a1 = m01 > m2 ? m2 : m01;
        a2 = n2;
    }
    unsigned ck[NCAND];
#pragma unroll
    for (int i = 0; i < NCAND; ++i) {
        unsigned m = a0;
#pragma unroll
        for (int s = 1; s < 64; s <<= 1) {
            unsigned o = (unsigned)__shfl_xor((int)m, s, 64);
            m = m > o ? m : o;
        }
        ck[i] = m;
        if (a0 == m) { a0 = a1; a1 = a2; a2 = 0; }
    }
    int cj[NCAND];
#pragma unroll
    for (int i = 0; i < NCAND; ++i) cj[i] = 8191 - (int)(ck[i] & 0x1FFFu);

    const float* pr = proj + (size_t)r * DD;
    float myp[8];
#pragma unroll
    for (int k = 0; k < 8; ++k) myp[k] = pr[t * 8 + k];
    double part[NCAND];
#pragma unroll
    for (int i = 0; i < NCAND; ++i) {
        const float* pc = proj + (size_t)cj[i] * DD;
        double s = 0.0;
#pragma unroll
        for (int k = 0; k < 8; ++k) s += (double)myp[k] * (double)pc[t * 8 + k];
        part[i] = s;
    }
#pragma unroll
    for (int i = 0; i < NCAND; ++i) {
#pragma unroll
        for (int s = 1; s < 64; s <<= 1) part[i] += __shfl_xor(part[i], s, 64);
    }
    double bv0 = -1e300, bv1 = -1e300, bv2 = -1e300;
    int bj0 = 0x7fffffff, bj1 = 0x7fffffff, bj2 = 0x7fffffff;
#pragma unroll
    for (int i = 0; i < NCAND; ++i) {
        double v = part[i]; int j = cj[i];
        bool g2 = (v > bv2) || (v == bv2 && j < bj2);
        bool g1 = (v > bv1) || (v == bv1 && j < bj1);
        bool g0 = (v > bv0) || (v == bv0 && j < bj0);
        if (g2) {
            if (g1) {
                if (g0) { bv2 = bv1; bj2 = bj1; bv1 = bv0; bj1 = bj0; bv0 = v; bj0 = j; }
                else    { bv2 = bv1; bj2 = bj1; bv1 = v; bj1 = j; }
            } else      { bv2 = v; bj2 = j; }
        }
    }
    double e1 = exp(bv1 - bv0), e2 = exp(bv2 - bv0);
    double inv = 1.0 / (1.0 + e1 + e2);
    float w0 = (float)inv, w1 = (float)(e1 * inv), w2 = (float)(e2 * inv);
    if (t == 0) {
        cos_out[r * 3 + 0] = w0; cos_out[r * 3 + 1] = w1; cos_out[r * 3 + 2] = w2;
    }
    const float4* s0 = (const float4*)(sess + (size_t)bj0 * DD);
    const float4* s1 = (const float4*)(sess + (size_t)bj1 * DD);
    const float4* s2 = (const float4*)(sess + (size_t)bj2 * DD);
    float4* o = (float4*)(out + (size_t)r * 3 * DD);
    float4* nb = (float4*)(out + (size_t)NB * 3 * DD + (size_t)r * DD);
#pragma unroll
    for (int e = 0; e < 2; ++e) {
        int q = t + e * 64;
        float4 x0 = s0[q], x1 = s1[q], x2 = s2[q];
        o[q] = x0; o[128 + q] = x1; o[256 + q] = x2;
        float4 v;
        v.x = fmaf(w0, x0.x, fmaf(w1, x1.x, w2 * x2.x));
        v.y = fmaf(w0, x0.y, fmaf(w1, x1.y, w2 * x2.y));
        v.z = fmaf(w0, x0.z, fmaf(w1, x1.z, w2 * x2.z));
        v.w = fmaf(w0, x0.w, fmaf(w1, x1.w, w2 * x2.w));
        nb[q] = v;
    }
}

extern "C" void kernel_launch(void* const* d_in, const int* in_sizes, int n_in,
                              void* d_out, int out_size, void* d_ws, size_t ws_size,
                              hipStream_t stream) {
    const float* sess = (const float*)d_in[0];
    // d_in[1] = pool_emb: unused by the reference
    const float* W1 = (const float*)d_in[2];
    const float* b1 = (const float*)d_in[3];
    const float* W2 = (const float*)d_in[4];
    const float* b2 = (const float*)d_in[5];
    float* out = (float*)d_out;

    const size_t MBc = 1u << 20;
    char* W = (char*)d_ws;
    float*   proj    = (float*)W;
    ushortT* sess_hi = (ushortT*)W;
    ushortT* sess_lo = sess_hi + (size_t)NB * DD;
    ushortT* projb   = (ushortT*)(W + 16 * MBc);
    ushortT* h_hi    = (ushortT*)(W + 24 * MBc);
    ushortT* h_lo    = (ushortT*)(W + 28 * MBc);
    ushortT* w1t_hi  = (ushortT*)(W + 32 * MBc);
    ushortT* w1t_lo  = w1t_hi + 256 * 512;
    ushortT* w2t_hi  = w1t_lo + 256 * 512;
    ushortT* w2t_lo  = w2t_hi + 512 * 256;
    unsigned* pkeys  = (unsigned*)(W + 24 * MBc);   // overlays h_hi/h_lo after gemm2

    float* cos_out = out + (size_t)NB * 3 * DD + (size_t)NB * DD;

    hipLaunchKernelGGL(prep_kernel, dim3(2176), dim3(256), 0, stream,
                       sess, W1, W2, sess_hi, sess_lo, w1t_hi, w1t_lo, w2t_hi, w2t_lo);
    hipLaunchKernelGGL((mlp_gemm<512, 256, 0, 32>), dim3(NB / 32, 1), dim3(256), 0, stream,
                       sess_hi, sess_lo, w1t_hi, w1t_lo, b1, h_hi, h_lo, (float*)nullptr, (ushortT*)nullptr);
    hipLaunchKernelGGL((mlp_gemm<256, 512, 1, 64>), dim3(NB / 64, 2), dim3(256), 0, stream,
                       h_hi, h_lo, w2t_hi, w2t_lo, b2, (ushortT*)nullptr, (ushortT*)nullptr, proj, projb);
    hipLaunchKernelGGL(sim_mfma_kernel, dim3(NTRI), dim3(256), 0, stream,
                       (const short*)projb, pkeys);
    hipLaunchKernelGGL(rerank_out_kernel, dim3(NB / 4), dim3(256), 0, stream,
                       proj, pkeys, sess, out, cos_out);
}